// Round 1
// baseline (1656.632 us; speedup 1.0000x reference)
//
#include <hip/hip_runtime.h>
#include <math.h>

#define SEQ 2048
#define DIM 1024
#define NH 16
#define FDIM 16
#define HDIM 64
#define WINSZ 256

// ---------------- fp32 GEMM: C[M,N] = A[M,K] @ B[K,N] (optionally += ) ------
__global__ __launch_bounds__(256) void gemm_f32(
    const float* __restrict__ A, const float* __restrict__ B,
    float* __restrict__ C, int M, int N, int K, int accumulate)
{
    __shared__ float As[16][64];   // [k][m]
    __shared__ float Bs[16][68];   // [k][n] (padded)
    const int tid = threadIdx.x;
    const int bm = blockIdx.y * 64;
    const int bn = blockIdx.x * 64;
    const int tr = (tid >> 4) * 4;
    const int tc = (tid & 15) * 4;
    const int ar = tid >> 2;          // A loader: row 0..63
    const int ac = (tid & 3) * 4;     //           k-col 0,4,8,12
    const int br = tid >> 4;          // B loader: k-row 0..15
    const int bc = (tid & 15) * 4;    //           col
    float acc[4][4] = {{0.f}};
    for (int k0 = 0; k0 < K; k0 += 16) {
        float4 a4 = *(const float4*)(A + (size_t)(bm + ar) * K + (k0 + ac));
        As[ac + 0][ar] = a4.x;
        As[ac + 1][ar] = a4.y;
        As[ac + 2][ar] = a4.z;
        As[ac + 3][ar] = a4.w;
        *(float4*)&Bs[br][bc] = *(const float4*)(B + (size_t)(k0 + br) * N + (bn + bc));
        __syncthreads();
#pragma unroll
        for (int k = 0; k < 16; ++k) {
            const float a0 = As[k][tr+0], a1 = As[k][tr+1], a2 = As[k][tr+2], a3 = As[k][tr+3];
            const float b0 = Bs[k][tc+0], b1 = Bs[k][tc+1], b2 = Bs[k][tc+2], b3 = Bs[k][tc+3];
            acc[0][0] += a0*b0; acc[0][1] += a0*b1; acc[0][2] += a0*b2; acc[0][3] += a0*b3;
            acc[1][0] += a1*b0; acc[1][1] += a1*b1; acc[1][2] += a1*b2; acc[1][3] += a1*b3;
            acc[2][0] += a2*b0; acc[2][1] += a2*b1; acc[2][2] += a2*b2; acc[2][3] += a2*b3;
            acc[3][0] += a3*b0; acc[3][1] += a3*b1; acc[3][2] += a3*b2; acc[3][3] += a3*b3;
        }
        __syncthreads();
    }
#pragma unroll
    for (int i = 0; i < 4; ++i) {
        float* p = C + (size_t)(bm + tr + i) * N + (bn + tc);
        float4 r = make_float4(acc[i][0], acc[i][1], acc[i][2], acc[i][3]);
        if (accumulate) {
            float4 o = *(const float4*)p;
            r.x += o.x; r.y += o.y; r.z += o.z; r.w += o.w;
        }
        *(float4*)p = r;
    }
}

// ---------------- linear (Taylor feature) attention, collapsed scores -------
// score(q,k) = 1 + (q.k)/4 + (q.k)^2/32 ; causal; out = (A v) / (rowsum(A)+eps)
__global__ __launch_bounds__(256) void lin_attn(
    const float* __restrict__ q,   // [SEQ, NH*FDIM]
    const float* __restrict__ k,   // [SEQ, NH*FDIM]
    const float* __restrict__ v,   // [SEQ, DIM] (head h at col h*HDIM)
    float* __restrict__ o)         // [SEQ, DIM]
{
    __shared__ float Ks[64][20];
    __shared__ float Vs[64][68];
    const int h  = blockIdx.y;
    const int qt = blockIdx.x;
    const int tid = threadIdx.x;
    const int ql = tid >> 2;       // local query 0..63
    const int dg = tid & 3;        // d-group (16 dims each)
    const int s  = qt * 64 + ql;
    float qv[16];
#pragma unroll
    for (int f4 = 0; f4 < 4; ++f4) {
        float4 t = *(const float4*)(q + (size_t)s * (NH*FDIM) + h * FDIM + f4 * 4);
        qv[f4*4+0] = t.x; qv[f4*4+1] = t.y; qv[f4*4+2] = t.z; qv[f4*4+3] = t.w;
    }
    float acc[16] = {0.f};
    float denom = 0.f;
    const int kr = tid >> 2, kc = (tid & 3) * 4;
    const int vr = tid >> 4, vc = (tid & 15) * 4;
    for (int kt = 0; kt <= qt; ++kt) {
        *(float4*)&Ks[kr][kc] =
            *(const float4*)(k + (size_t)(kt*64 + kr) * (NH*FDIM) + h * FDIM + kc);
#pragma unroll
        for (int rr = 0; rr < 4; ++rr)
            *(float4*)&Vs[vr + rr*16][vc] =
                *(const float4*)(v + (size_t)(kt*64 + vr + rr*16) * DIM + h * HDIM + vc);
        __syncthreads();
        const int tmax = (kt == qt) ? (ql + 1) : 64;
        for (int t = 0; t < tmax; ++t) {
            float dot = 0.f;
#pragma unroll
            for (int f = 0; f < 16; ++f) dot += qv[f] * Ks[t][f];
            const float sc = 1.f + 0.25f * dot + dot * dot * (1.f / 32.f);
            denom += sc;
#pragma unroll
            for (int j = 0; j < 16; ++j) acc[j] += sc * Vs[t][dg*16 + j];
        }
        __syncthreads();
    }
    const float inv = 1.f / (denom + 1e-9f);
#pragma unroll
    for (int j4 = 0; j4 < 4; ++j4) {
        float4 r = make_float4(acc[j4*4+0]*inv, acc[j4*4+1]*inv,
                               acc[j4*4+2]*inv, acc[j4*4+3]*inv);
        *(float4*)(o + (size_t)s * DIM + h * HDIM + dg*16 + j4*4) = r;
    }
}

// ---------------- banded softmax attention (j <= i + W - 1, no lower bound) -
__global__ __launch_bounds__(256) void win_attn(
    const float* __restrict__ q,   // [SEQ, DIM]
    const float* __restrict__ k,   // [SEQ, DIM]
    const float* __restrict__ v,   // [SEQ, DIM]
    const int* __restrict__ amask, // [SEQ]
    float* __restrict__ o)         // [SEQ, DIM]
{
    __shared__ float Ks[64][68];
    __shared__ float Vs[64][68];
    __shared__ int   Ms[64];
    const int h  = blockIdx.y;
    const int qt = blockIdx.x;
    const int tid = threadIdx.x;
    const int ql = tid >> 2;
    const int dg = tid & 3;
    const int s  = qt * 64 + ql;
    float qv[16];
#pragma unroll
    for (int f4 = 0; f4 < 4; ++f4) {
        float4 t = *(const float4*)(q + (size_t)s * DIM + h * HDIM + dg*16 + f4*4);
        qv[f4*4+0] = t.x; qv[f4*4+1] = t.y; qv[f4*4+2] = t.z; qv[f4*4+3] = t.w;
    }
    float acc[16] = {0.f};
    float m = -INFINITY, l = 0.f;
    const int vr = tid >> 4, vc = (tid & 15) * 4;
    const int ktEnd = min(SEQ/64 - 1, qt + 4);
    for (int kt = 0; kt <= ktEnd; ++kt) {
#pragma unroll
        for (int rr = 0; rr < 4; ++rr) {
            *(float4*)&Ks[vr + rr*16][vc] =
                *(const float4*)(k + (size_t)(kt*64 + vr + rr*16) * DIM + h * HDIM + vc);
            *(float4*)&Vs[vr + rr*16][vc] =
                *(const float4*)(v + (size_t)(kt*64 + vr + rr*16) * DIM + h * HDIM + vc);
        }
        if (tid < 64) Ms[tid] = amask[kt*64 + tid];
        __syncthreads();
        for (int t = 0; t < 64; ++t) {
            float part = 0.f;
#pragma unroll
            for (int f = 0; f < 16; ++f) part += qv[f] * Ks[t][dg*16 + f];
            part += __shfl_xor(part, 1);
            part += __shfl_xor(part, 2);     // all 4 lanes now hold full 64-dim dot
            const int jg = kt*64 + t;
            const bool ok = (jg <= s + (WINSZ - 1)) && (Ms[t] != 0);
            const float sc = ok ? part * 0.125f : -INFINITY;   // 1/sqrt(64)
            const float mn = fmaxf(m, sc);
            const float corr = (m == -INFINITY) ? 0.f : __expf(m - mn);
            const float p = ok ? __expf(sc - mn) : 0.f;
            l = l * corr + p;
#pragma unroll
            for (int j = 0; j < 16; ++j)
                acc[j] = acc[j] * corr + p * Vs[t][dg*16 + j];
            m = mn;
        }
        __syncthreads();
    }
    const float invl = 1.f / l;
#pragma unroll
    for (int j4 = 0; j4 < 4; ++j4) {
        float4 r = make_float4(acc[j4*4+0]*invl, acc[j4*4+1]*invl,
                               acc[j4*4+2]*invl, acc[j4*4+3]*invl);
        *(float4*)(o + (size_t)s * DIM + h * HDIM + dg*16 + j4*4) = r;
    }
}

extern "C" void kernel_launch(void* const* d_in, const int* in_sizes, int n_in,
                              void* d_out, int out_size, void* d_ws, size_t ws_size,
                              hipStream_t stream) {
    const float* h      = (const float*)d_in[0];
    const int*   amask  = (const int*)d_in[1];
    const float* lin_Wq = (const float*)d_in[2];
    const float* lin_Wk = (const float*)d_in[3];
    const float* lin_Wv = (const float*)d_in[4];
    const float* lin_Wo = (const float*)d_in[5];
    const float* win_Wq = (const float*)d_in[6];
    const float* win_Wk = (const float*)d_in[7];
    const float* win_Wv = (const float*)d_in[8];
    const float* win_Wo = (const float*)d_in[9];
    float* out = (float*)d_out;

    float* ws   = (float*)d_ws;
    float* qlin = ws;                       // [SEQ, 256]
    float* klin = qlin + SEQ * (NH*FDIM);   // [SEQ, 256]
    float* vlin = klin + SEQ * (NH*FDIM);   // [SEQ, DIM]
    float* qw   = vlin + SEQ * DIM;
    float* kw   = qw   + SEQ * DIM;
    float* vw   = kw   + SEQ * DIM;
    float* latt = vw   + SEQ * DIM;
    float* watt = latt + SEQ * DIM;

    const dim3 blk(256);
    const dim3 gP(((NH*FDIM))/64, SEQ/64);   // N=256 projections
    const dim3 gD(DIM/64, SEQ/64);           // N=1024 GEMMs
    gemm_f32<<<gP, blk, 0, stream>>>(h, lin_Wq, qlin, SEQ, NH*FDIM, DIM, 0);
    gemm_f32<<<gP, blk, 0, stream>>>(h, lin_Wk, klin, SEQ, NH*FDIM, DIM, 0);
    gemm_f32<<<gD, blk, 0, stream>>>(h, lin_Wv, vlin, SEQ, DIM, DIM, 0);
    gemm_f32<<<gD, blk, 0, stream>>>(h, win_Wq, qw,   SEQ, DIM, DIM, 0);
    gemm_f32<<<gD, blk, 0, stream>>>(h, win_Wk, kw,   SEQ, DIM, DIM, 0);
    gemm_f32<<<gD, blk, 0, stream>>>(h, win_Wv, vw,   SEQ, DIM, DIM, 0);

    lin_attn<<<dim3(SEQ/64, NH), blk, 0, stream>>>(qlin, klin, vlin, latt);
    win_attn<<<dim3(SEQ/64, NH), blk, 0, stream>>>(qw, kw, vw, amask, watt);

    gemm_f32<<<gD, blk, 0, stream>>>(latt, lin_Wo, out, SEQ, DIM, DIM, 0);
    gemm_f32<<<gD, blk, 0, stream>>>(watt, win_Wo, out, SEQ, DIM, DIM, 1);
}

// Round 2
// 329.524 us; speedup vs baseline: 5.0274x; 5.0274x over previous
//
#include <hip/hip_runtime.h>
#include <hip/hip_bf16.h>
#include <math.h>

#define SEQ 2048
#define DIM 1024
#define NH 16
#define FDIM 16

typedef __bf16 bf16x8 __attribute__((ext_vector_type(8)));
typedef float f32x4 __attribute__((ext_vector_type(4)));
typedef __hip_bfloat16 bf16g;

__device__ __forceinline__ void gld16(const void* g, void* l) {
    __builtin_amdgcn_global_load_lds((const __attribute__((address_space(1))) void*)g,
                                     (__attribute__((address_space(3))) void*)l, 16, 0, 0);
}

// Stage a 64-row x 64-col bf16 tile (8KB) into LDS with 16B-chunk XOR swizzle.
// Slot gg of row holds source chunk gg ^ (row & 7).
__device__ __forceinline__ void stage64(char* lds, const bf16g* src, int stride, int tid) {
#pragma unroll
    for (int c = 0; c < 2; ++c) {
        const int idx = ((tid >> 6) * 128) + c * 64 + (tid & 63);
        const int row = idx >> 3, gg = idx & 7;
        const bf16g* gp = src + (size_t)row * stride + ((gg ^ (row & 7)) * 8);
        char* lp = lds + (((tid >> 6) * 128) + c * 64) * 16;
        gld16(gp, lp);
    }
}

// Stage a 128-row x 64-col bf16 tile (16KB).
__device__ __forceinline__ void stage128(char* lds, const bf16g* src, int stride, int tid) {
#pragma unroll
    for (int c = 0; c < 4; ++c) {
        const int idx = ((tid >> 6) * 256) + c * 64 + (tid & 63);
        const int row = idx >> 3, gg = idx & 7;
        const bf16g* gp = src + (size_t)row * stride + ((gg ^ (row & 7)) * 8);
        char* lp = lds + (((tid >> 6) * 256) + c * 64) * 16;
        gld16(gp, lp);
    }
}

// Read 8 contiguous bf16 at (row, kbase) from a 64-col swizzled tile (row stride 128B).
__device__ __forceinline__ bf16x8 frag64(const char* lds, int row, int kbase) {
    const int ch = kbase >> 3;
    return *(const bf16x8*)(lds + row * 128 + ((ch ^ (row & 7)) << 4));
}
// Same for 32-col tiles (row stride 64B, 4 chunks).
__device__ __forceinline__ bf16x8 frag32(const char* lds, int row, int kbase) {
    const int ch = kbase >> 3;
    return *(const bf16x8*)(lds + row * 64 + ((ch ^ (row & 3)) << 4));
}

// ------------------- prep kernels -------------------
__global__ __launch_bounds__(256) void convert_h(const float* __restrict__ in, bf16g* __restrict__ out) {
    const size_t base = ((size_t)blockIdx.x * 256 + threadIdx.x) * 8;
    float4 a = *(const float4*)(in + base);
    float4 b = *(const float4*)(in + base + 4);
    __attribute__((aligned(16))) bf16g t[8];
    t[0] = __float2bfloat16(a.x); t[1] = __float2bfloat16(a.y);
    t[2] = __float2bfloat16(a.z); t[3] = __float2bfloat16(a.w);
    t[4] = __float2bfloat16(b.x); t[5] = __float2bfloat16(b.y);
    t[6] = __float2bfloat16(b.z); t[7] = __float2bfloat16(b.w);
    *(uint4*)(out + base) = *(const uint4*)t;
}

// in: f32 [R][C]  ->  out: bf16 [C][R]
__global__ __launch_bounds__(256) void transpose_f32_bf16(const float* __restrict__ in,
                                                          bf16g* __restrict__ out, int R, int C) {
    __shared__ float T[32][33];
    const int tid = threadIdx.x;
    const int br = blockIdx.y * 32, bc = blockIdx.x * 32;
    const int r = tid >> 3, c4 = (tid & 7) * 4;
    float4 v = *(const float4*)(in + (size_t)(br + r) * C + bc + c4);
    T[r][c4 + 0] = v.x; T[r][c4 + 1] = v.y; T[r][c4 + 2] = v.z; T[r][c4 + 3] = v.w;
    __syncthreads();
    const int c = tid >> 3, r4 = (tid & 7) * 4;
    __attribute__((aligned(8))) bf16g o[4];
#pragma unroll
    for (int i = 0; i < 4; ++i) o[i] = __float2bfloat16(T[r4 + i][c]);
    *(ushort4*)(out + (size_t)(bc + c) * R + br + r4) = *(const ushort4*)o;
}

// in: bf16 [R][C] -> out: bf16 [C][R]
__global__ __launch_bounds__(256) void transpose_bf16(const bf16g* __restrict__ in,
                                                      bf16g* __restrict__ out, int R, int C) {
    __shared__ unsigned short T[32][33];
    const int tid = threadIdx.x;
    const int br = blockIdx.y * 32, bc = blockIdx.x * 32;
    const int r = tid >> 3, c4 = (tid & 7) * 4;
    ushort4 v = *(const ushort4*)((const unsigned short*)in + (size_t)(br + r) * C + bc + c4);
    T[r][c4 + 0] = v.x; T[r][c4 + 1] = v.y; T[r][c4 + 2] = v.z; T[r][c4 + 3] = v.w;
    __syncthreads();
    const int c = tid >> 3, r4 = (tid & 7) * 4;
    ushort4 o;
    o.x = T[r4 + 0][c]; o.y = T[r4 + 1][c]; o.z = T[r4 + 2][c]; o.w = T[r4 + 3][c];
    *(ushort4*)((unsigned short*)out + (size_t)(bc + c) * R + br + r4) = o;
}

__global__ __launch_bounds__(256) void make_bias(const int* __restrict__ amask, float* __restrict__ bias) {
    const int t = blockIdx.x * 256 + threadIdx.x;
    if (t < SEQ) bias[t] = (amask[t] != 0) ? 0.f : -1e30f;
}

// ------------------- bf16 MFMA GEMM -------------------
// C[M,N] = A[M,K] @ BT[N,K]^T.  MODE 0: bf16 out; 1: f32 out; 2: f32 +=
template <int MODE>
__global__ __launch_bounds__(256) void gemm_bf16(const bf16g* __restrict__ A,
                                                 const bf16g* __restrict__ BT,
                                                 float* __restrict__ Cf, bf16g* __restrict__ Cb,
                                                 int M, int N, int K) {
    __shared__ char As[16384];
    __shared__ char Bs[16384];
    const int tid = threadIdx.x, lane = tid & 63, w = tid >> 6;
    const int wr = (w >> 1) * 64, wc = (w & 1) * 64;
    const int bm = blockIdx.y * 128, bn = blockIdx.x * 128;
    const int l15 = lane & 15, l4 = lane >> 4;
    f32x4 z = {0.f, 0.f, 0.f, 0.f};
    f32x4 acc[4][4];
#pragma unroll
    for (int m = 0; m < 4; ++m)
#pragma unroll
        for (int n = 0; n < 4; ++n) acc[m][n] = z;

    for (int k0 = 0; k0 < K; k0 += 64) {
        stage128(As, A + (size_t)bm * K + k0, K, tid);
        stage128(Bs, BT + (size_t)bn * K + k0, K, tid);
        __syncthreads();
#pragma unroll
        for (int kk = 0; kk < 2; ++kk) {
            const int kb = kk * 32 + l4 * 8;
            bf16x8 a[4], b[4];
#pragma unroll
            for (int m = 0; m < 4; ++m) a[m] = frag64(As, wr + m * 16 + l15, kb);
#pragma unroll
            for (int n = 0; n < 4; ++n) b[n] = frag64(Bs, wc + n * 16 + l15, kb);
#pragma unroll
            for (int m = 0; m < 4; ++m)
#pragma unroll
                for (int n = 0; n < 4; ++n)
                    acc[m][n] = __builtin_amdgcn_mfma_f32_16x16x32_bf16(a[m], b[n], acc[m][n], 0, 0, 0);
        }
        __syncthreads();
    }
#pragma unroll
    for (int m = 0; m < 4; ++m)
#pragma unroll
        for (int n = 0; n < 4; ++n)
#pragma unroll
            for (int r = 0; r < 4; ++r) {
                const size_t off = (size_t)(bm + wr + m * 16 + l4 * 4 + r) * N + bn + wc + n * 16 + l15;
                if (MODE == 0) Cb[off] = __float2bfloat16(acc[m][n][r]);
                else if (MODE == 1) Cf[off] = acc[m][n][r];
                else Cf[off] += acc[m][n][r];
            }
}

// ------------------- banded softmax attention (MFMA) -------------------
__global__ __launch_bounds__(256) void win_attn_mfma(const bf16g* __restrict__ Q,
                                                     const bf16g* __restrict__ Kg,
                                                     const bf16g* __restrict__ VT,
                                                     const float* __restrict__ bias,
                                                     bf16g* __restrict__ O) {
    __shared__ char Qs[8192];
    __shared__ char Ks[8192];
    __shared__ char Vs[8192];
    __shared__ char Ps[8192];
    const int tid = threadIdx.x, lane = tid & 63, w = tid >> 6;
    const int h = blockIdx.y, qt = blockIdx.x;
    const int l15 = lane & 15, l4 = lane >> 4;
    char* Pw = Ps + w * 2048;

    stage64(Qs, Q + (size_t)(qt * 64) * DIM + h * 64, DIM, tid);

    f32x4 zero4 = {0.f, 0.f, 0.f, 0.f};
    f32x4 acc[4];
    float m_[4], l_[4];
#pragma unroll
    for (int n = 0; n < 4; ++n) acc[n] = zero4;
#pragma unroll
    for (int r = 0; r < 4; ++r) { m_[r] = -1e30f; l_[r] = 0.f; }

    bf16x8 aq0, aq1;
    const int ktEnd = min(SEQ / 64 - 1, qt + 4);
    for (int kt = 0; kt <= ktEnd; ++kt) {
        stage64(Ks, Kg + (size_t)(kt * 64) * DIM + h * 64, DIM, tid);
        stage64(Vs, VT + (size_t)(h * 64) * SEQ + kt * 64, SEQ, tid);
        __syncthreads();
        if (kt == 0) {
            aq0 = frag64(Qs, w * 16 + l15, l4 * 8);
            aq1 = frag64(Qs, w * 16 + l15, 32 + l4 * 8);
        }
        f32x4 s[4];
#pragma unroll
        for (int n = 0; n < 4; ++n) {
            f32x4 t = zero4;
            t = __builtin_amdgcn_mfma_f32_16x16x32_bf16(aq0, frag64(Ks, n * 16 + l15, l4 * 8), t, 0, 0, 0);
            t = __builtin_amdgcn_mfma_f32_16x16x32_bf16(aq1, frag64(Ks, n * 16 + l15, 32 + l4 * 8), t, 0, 0, 0);
            s[n] = t;
        }
        // scale + masks
#pragma unroll
        for (int n = 0; n < 4; ++n) {
            const float ab = bias[kt * 64 + n * 16 + l15];
#pragma unroll
            for (int r = 0; r < 4; ++r) {
                float sc = s[n][r] * 0.125f + ab;
                if (kt == qt + 4) {
                    const int sg = qt * 64 + w * 16 + l4 * 4 + r;
                    const int tg = kt * 64 + n * 16 + l15;
                    if (tg > sg + 255) sc = -1e30f;
                }
                s[n][r] = sc;
            }
        }
        // row max over 64 cols
        float tm[4];
#pragma unroll
        for (int r = 0; r < 4; ++r)
            tm[r] = fmaxf(fmaxf(s[0][r], s[1][r]), fmaxf(s[2][r], s[3][r]));
#pragma unroll
        for (int off = 1; off < 16; off <<= 1)
#pragma unroll
            for (int r = 0; r < 4; ++r) tm[r] = fmaxf(tm[r], __shfl_xor(tm[r], off));
        float corr[4], rs[4];
#pragma unroll
        for (int r = 0; r < 4; ++r) {
            const float mn = fmaxf(m_[r], tm[r]);
            corr[r] = __expf(m_[r] - mn);
            m_[r] = mn;
            rs[r] = 0.f;
        }
#pragma unroll
        for (int n = 0; n < 4; ++n)
#pragma unroll
            for (int r = 0; r < 4; ++r) {
                const float p = (s[n][r] > -1e29f) ? __expf(s[n][r] - m_[r]) : 0.f;
                s[n][r] = p;
                rs[r] += p;
            }
#pragma unroll
        for (int off = 1; off < 16; off <<= 1)
#pragma unroll
            for (int r = 0; r < 4; ++r) rs[r] += __shfl_xor(rs[r], off);
#pragma unroll
        for (int r = 0; r < 4; ++r) l_[r] = l_[r] * corr[r] + rs[r];
#pragma unroll
        for (int n = 0; n < 4; ++n)
#pragma unroll
            for (int r = 0; r < 4; ++r) acc[n][r] *= corr[r];
        // write P (bf16, swizzled) into this wave's private region
#pragma unroll
        for (int n = 0; n < 4; ++n)
#pragma unroll
            for (int r = 0; r < 4; ++r) {
                const int prow = l4 * 4 + r;
                const int pcol = n * 16 + l15;
                const int ch = pcol >> 3;
                *(bf16g*)(Pw + prow * 128 + ((ch ^ (prow & 7)) << 4) + (pcol & 7) * 2) =
                    __float2bfloat16(s[n][r]);
            }
        // PV
#pragma unroll
        for (int kk = 0; kk < 2; ++kk) {
            bf16x8 pa = frag64(Pw, l15, kk * 32 + l4 * 8);
#pragma unroll
            for (int n = 0; n < 4; ++n)
                acc[n] = __builtin_amdgcn_mfma_f32_16x16x32_bf16(
                    pa, frag64(Vs, n * 16 + l15, kk * 32 + l4 * 8), acc[n], 0, 0, 0);
        }
        __syncthreads();
    }
#pragma unroll
    for (int n = 0; n < 4; ++n)
#pragma unroll
        for (int r = 0; r < 4; ++r) {
            const int sg = qt * 64 + w * 16 + l4 * 4 + r;
            O[(size_t)sg * DIM + h * 64 + n * 16 + l15] = __float2bfloat16(acc[n][r] / l_[r]);
        }
}

// ------------------- linear (Taylor) attention (MFMA) -------------------
__global__ __launch_bounds__(256) void lin_attn_mfma(const bf16g* __restrict__ Qe,
                                                     const bf16g* __restrict__ Ke,
                                                     const bf16g* __restrict__ VT,
                                                     bf16g* __restrict__ O) {
    __shared__ char Qs[4096];
    __shared__ char Ks[4096];
    __shared__ char Vs[8192];
    __shared__ char Ps[8192];
    const int tid = threadIdx.x, lane = tid & 63, w = tid >> 6;
    const int h = blockIdx.y, qt = blockIdx.x;
    const int l15 = lane & 15, l4 = lane >> 4;
    char* Pw = Ps + w * 2048;

    const int row = tid >> 2, gp = tid & 3, g = gp ^ (row & 3);
    const uint4 z4 = {0u, 0u, 0u, 0u};
    // stage Q zero-padded [64][32] (cols 16..31 zero)
    {
        uint4 qv = (g < 2) ? *(const uint4*)(Qe + (size_t)(qt * 64 + row) * (NH * FDIM) + h * FDIM + g * 8)
                           : z4;
        *(uint4*)(Qs + row * 64 + gp * 16) = qv;
    }
    f32x4 zero4 = {0.f, 0.f, 0.f, 0.f};
    f32x4 acc[4];
    float den[4] = {0.f, 0.f, 0.f, 0.f};
#pragma unroll
    for (int n = 0; n < 4; ++n) acc[n] = zero4;
    bf16x8 aq;

    for (int kt = 0; kt <= qt; ++kt) {
        uint4 kv = (g < 2) ? *(const uint4*)(Ke + (size_t)(kt * 64 + row) * (NH * FDIM) + h * FDIM + g * 8)
                           : z4;
        __syncthreads();   // previous tile's reads done before overwrite
        *(uint4*)(Ks + row * 64 + gp * 16) = kv;
        stage64(Vs, VT + (size_t)(h * 64) * SEQ + kt * 64, SEQ, tid);
        __syncthreads();
        if (kt == 0) aq = frag32(Qs, w * 16 + l15, l4 * 8);
        f32x4 s[4];
#pragma unroll
        for (int n = 0; n < 4; ++n)
            s[n] = __builtin_amdgcn_mfma_f32_16x16x32_bf16(aq, frag32(Ks, n * 16 + l15, l4 * 8), zero4, 0, 0, 0);
        float rs[4] = {0.f, 0.f, 0.f, 0.f};
#pragma unroll
        for (int n = 0; n < 4; ++n)
#pragma unroll
            for (int r = 0; r < 4; ++r) {
                const float d = s[n][r];
                float sc = 1.f + 0.25f * d + d * d * (1.f / 32.f);
                if (kt == qt) {
                    const int sg = w * 16 + l4 * 4 + r;
                    const int tg = n * 16 + l15;
                    if (tg > sg) sc = 0.f;
                }
                s[n][r] = sc;
                rs[r] += sc;
            }
#pragma unroll
        for (int off = 1; off < 16; off <<= 1)
#pragma unroll
            for (int r = 0; r < 4; ++r) rs[r] += __shfl_xor(rs[r], off);
#pragma unroll
        for (int r = 0; r < 4; ++r) den[r] += rs[r];
#pragma unroll
        for (int n = 0; n < 4; ++n)
#pragma unroll
            for (int r = 0; r < 4; ++r) {
                const int prow = l4 * 4 + r;
                const int pcol = n * 16 + l15;
                const int ch = pcol >> 3;
                *(bf16g*)(Pw + prow * 128 + ((ch ^ (prow & 7)) << 4) + (pcol & 7) * 2) =
                    __float2bfloat16(s[n][r]);
            }
#pragma unroll
        for (int kk = 0; kk < 2; ++kk) {
            bf16x8 pa = frag64(Pw, l15, kk * 32 + l4 * 8);
#pragma unroll
            for (int n = 0; n < 4; ++n)
                acc[n] = __builtin_amdgcn_mfma_f32_16x16x32_bf16(
                    pa, frag64(Vs, n * 16 + l15, kk * 32 + l4 * 8), acc[n], 0, 0, 0);
        }
    }
#pragma unroll
    for (int n = 0; n < 4; ++n)
#pragma unroll
        for (int r = 0; r < 4; ++r) {
            const int sg = qt * 64 + w * 16 + l4 * 4 + r;
            O[(size_t)sg * DIM + h * 64 + n * 16 + l15] =
                __float2bfloat16(acc[n][r] / (den[r] + 1e-9f));
        }
}

// ------------------- host -------------------
extern "C" void kernel_launch(void* const* d_in, const int* in_sizes, int n_in,
                              void* d_out, int out_size, void* d_ws, size_t ws_size,
                              hipStream_t stream) {
    const float* h      = (const float*)d_in[0];
    const int*   amask  = (const int*)d_in[1];
    const float* lin_Wq = (const float*)d_in[2];
    const float* lin_Wk = (const float*)d_in[3];
    const float* lin_Wv = (const float*)d_in[4];
    const float* lin_Wo = (const float*)d_in[5];
    const float* win_Wq = (const float*)d_in[6];
    const float* win_Wk = (const float*)d_in[7];
    const float* win_Wv = (const float*)d_in[8];
    const float* win_Wo = (const float*)d_in[9];
    float* out = (float*)d_out;

    char* p = (char*)d_ws;
    bf16g* h_b   = (bf16g*)p; p += (size_t)SEQ * DIM * 2;
    bf16g* WqlT  = (bf16g*)p; p += (size_t)(NH * FDIM) * DIM * 2;
    bf16g* WklT  = (bf16g*)p; p += (size_t)(NH * FDIM) * DIM * 2;
    bf16g* WvlT  = (bf16g*)p; p += (size_t)DIM * DIM * 2;
    bf16g* WolT  = (bf16g*)p; p += (size_t)DIM * DIM * 2;
    bf16g* WqwT  = (bf16g*)p; p += (size_t)DIM * DIM * 2;
    bf16g* WkwT  = (bf16g*)p; p += (size_t)DIM * DIM * 2;
    bf16g* WvwT  = (bf16g*)p; p += (size_t)DIM * DIM * 2;
    bf16g* WowT  = (bf16g*)p; p += (size_t)DIM * DIM * 2;
    bf16g* qlin  = (bf16g*)p; p += (size_t)SEQ * (NH * FDIM) * 2;
    bf16g* klin  = (bf16g*)p; p += (size_t)SEQ * (NH * FDIM) * 2;
    bf16g* vlin  = (bf16g*)p; p += (size_t)SEQ * DIM * 2;
    bf16g* qw    = (bf16g*)p; p += (size_t)SEQ * DIM * 2;
    bf16g* kw    = (bf16g*)p; p += (size_t)SEQ * DIM * 2;
    bf16g* vw    = (bf16g*)p; p += (size_t)SEQ * DIM * 2;
    bf16g* vlinT = (bf16g*)p; p += (size_t)SEQ * DIM * 2;
    bf16g* vwT   = (bf16g*)p; p += (size_t)SEQ * DIM * 2;
    bf16g* latt  = (bf16g*)p; p += (size_t)SEQ * DIM * 2;
    bf16g* watt  = (bf16g*)p; p += (size_t)SEQ * DIM * 2;
    float* bias  = (float*)p; p += (size_t)SEQ * 4;

    const dim3 blk(256);
    convert_h<<<dim3(SEQ * DIM / 8 / 256), blk, 0, stream>>>(h, h_b);
    transpose_f32_bf16<<<dim3((NH*FDIM)/32, DIM/32), blk, 0, stream>>>(lin_Wq, WqlT, DIM, NH*FDIM);
    transpose_f32_bf16<<<dim3((NH*FDIM)/32, DIM/32), blk, 0, stream>>>(lin_Wk, WklT, DIM, NH*FDIM);
    transpose_f32_bf16<<<dim3(DIM/32, DIM/32), blk, 0, stream>>>(lin_Wv, WvlT, DIM, DIM);
    transpose_f32_bf16<<<dim3(DIM/32, DIM/32), blk, 0, stream>>>(lin_Wo, WolT, DIM, DIM);
    transpose_f32_bf16<<<dim3(DIM/32, DIM/32), blk, 0, stream>>>(win_Wq, WqwT, DIM, DIM);
    transpose_f32_bf16<<<dim3(DIM/32, DIM/32), blk, 0, stream>>>(win_Wk, WkwT, DIM, DIM);
    transpose_f32_bf16<<<dim3(DIM/32, DIM/32), blk, 0, stream>>>(win_Wv, WvwT, DIM, DIM);
    transpose_f32_bf16<<<dim3(DIM/32, DIM/32), blk, 0, stream>>>(win_Wo, WowT, DIM, DIM);
    make_bias<<<dim3(SEQ / 256), blk, 0, stream>>>(amask, bias);

    gemm_bf16<0><<<dim3((NH*FDIM)/128, SEQ/128), blk, 0, stream>>>(h_b, WqlT, nullptr, qlin, SEQ, NH*FDIM, DIM);
    gemm_bf16<0><<<dim3((NH*FDIM)/128, SEQ/128), blk, 0, stream>>>(h_b, WklT, nullptr, klin, SEQ, NH*FDIM, DIM);
    gemm_bf16<0><<<dim3(DIM/128, SEQ/128), blk, 0, stream>>>(h_b, WvlT, nullptr, vlin, SEQ, DIM, DIM);
    gemm_bf16<0><<<dim3(DIM/128, SEQ/128), blk, 0, stream>>>(h_b, WqwT, nullptr, qw, SEQ, DIM, DIM);
    gemm_bf16<0><<<dim3(DIM/128, SEQ/128), blk, 0, stream>>>(h_b, WkwT, nullptr, kw, SEQ, DIM, DIM);
    gemm_bf16<0><<<dim3(DIM/128, SEQ/128), blk, 0, stream>>>(h_b, WvwT, nullptr, vw, SEQ, DIM, DIM);

    transpose_bf16<<<dim3(DIM/32, SEQ/32), blk, 0, stream>>>(vlin, vlinT, SEQ, DIM);
    transpose_bf16<<<dim3(DIM/32, SEQ/32), blk, 0, stream>>>(vw, vwT, SEQ, DIM);

    lin_attn_mfma<<<dim3(SEQ/64, NH), blk, 0, stream>>>(qlin, klin, vlinT, latt);
    win_attn_mfma<<<dim3(SEQ/64, NH), blk, 0, stream>>>(qw, kw, vwT, bias, watt);

    gemm_bf16<1><<<dim3(DIM/128, SEQ/128), blk, 0, stream>>>(latt, WolT, out, nullptr, SEQ, DIM, DIM);
    gemm_bf16<2><<<dim3(DIM/128, SEQ/128), blk, 0, stream>>>(watt, WowT, out, nullptr, SEQ, DIM, DIM);
}

// Round 3
// 194.726 us; speedup vs baseline: 8.5075x; 1.6922x over previous
//
#include <hip/hip_runtime.h>
#include <hip/hip_bf16.h>
#include <math.h>

#define SEQ 2048
#define DIM 1024
#define NH 16
#define FDIM 16

typedef __bf16 bf16x8 __attribute__((ext_vector_type(8)));
typedef float f32x4 __attribute__((ext_vector_type(4)));
typedef __hip_bfloat16 bf16g;

__device__ __forceinline__ void gld16(const void* g, void* l) {
    __builtin_amdgcn_global_load_lds((const __attribute__((address_space(1))) void*)g,
                                     (__attribute__((address_space(3))) void*)l, 16, 0, 0);
}

// Stage a 64x64 bf16 tile (8KB) into LDS with 16B-chunk XOR swizzle.
__device__ __forceinline__ void stage64(char* lds, const bf16g* src, int stride, int tid) {
#pragma unroll
    for (int c = 0; c < 2; ++c) {
        const int idx = ((tid >> 6) * 128) + c * 64 + (tid & 63);
        const int row = idx >> 3, gg = idx & 7;
        const bf16g* gp = src + (size_t)row * stride + ((gg ^ (row & 7)) * 8);
        char* lp = lds + (((tid >> 6) * 128) + c * 64) * 16;
        gld16(gp, lp);
    }
}

// Stage a 128x64 bf16 tile (16KB).
__device__ __forceinline__ void stage128(char* lds, const bf16g* src, int stride, int tid) {
#pragma unroll
    for (int c = 0; c < 4; ++c) {
        const int idx = ((tid >> 6) * 256) + c * 64 + (tid & 63);
        const int row = idx >> 3, gg = idx & 7;
        const bf16g* gp = src + (size_t)row * stride + ((gg ^ (row & 7)) * 8);
        char* lp = lds + (((tid >> 6) * 256) + c * 64) * 16;
        gld16(gp, lp);
    }
}

__device__ __forceinline__ bf16x8 frag64(const char* lds, int row, int kbase) {
    const int ch = kbase >> 3;
    return *(const bf16x8*)(lds + row * 128 + ((ch ^ (row & 7)) << 4));
}
__device__ __forceinline__ bf16x8 frag32(const char* lds, int row, int kbase) {
    const int ch = kbase >> 3;
    return *(const bf16x8*)(lds + row * 64 + ((ch ^ (row & 3)) << 4));
}

// ------------------- prep kernels -------------------
__global__ __launch_bounds__(256) void convert_h(const float* __restrict__ in, bf16g* __restrict__ out) {
    const size_t base = ((size_t)blockIdx.x * 256 + threadIdx.x) * 8;
    float4 a = *(const float4*)(in + base);
    float4 b = *(const float4*)(in + base + 4);
    __attribute__((aligned(16))) bf16g t[8];
    t[0] = __float2bfloat16(a.x); t[1] = __float2bfloat16(a.y);
    t[2] = __float2bfloat16(a.z); t[3] = __float2bfloat16(a.w);
    t[4] = __float2bfloat16(b.x); t[5] = __float2bfloat16(b.y);
    t[6] = __float2bfloat16(b.z); t[7] = __float2bfloat16(b.w);
    *(uint4*)(out + base) = *(const uint4*)t;
}

// f32 [R][C] -> bf16 [C][ostride] (transposed, out row stride = ostride)
__global__ __launch_bounds__(256) void transpose_f32_bf16(const float* __restrict__ in,
                                                          bf16g* __restrict__ out,
                                                          int R, int C, int ostride) {
    __shared__ float T[32][33];
    const int tid = threadIdx.x;
    const int br = blockIdx.y * 32, bc = blockIdx.x * 32;
    const int r = tid >> 3, c4 = (tid & 7) * 4;
    float4 v = *(const float4*)(in + (size_t)(br + r) * C + bc + c4);
    T[r][c4 + 0] = v.x; T[r][c4 + 1] = v.y; T[r][c4 + 2] = v.z; T[r][c4 + 3] = v.w;
    __syncthreads();
    const int c = tid >> 3, r4 = (tid & 7) * 4;
    __attribute__((aligned(8))) bf16g o[4];
#pragma unroll
    for (int i = 0; i < 4; ++i) o[i] = __float2bfloat16(T[r4 + i][c]);
    *(ushort4*)(out + (size_t)(bc + c) * ostride + br + r4) = *(const ushort4*)o;
}

// batched: six 1024x1024 f32->bf16 transposes
struct TP6 { const float* src[6]; bf16g* dst[6]; int os[6]; };
__global__ __launch_bounds__(256) void transpose6(TP6 jp) {
    __shared__ float T[32][33];
    const int j = blockIdx.z;
    const float* in = jp.src[j];
    bf16g* out = jp.dst[j];
    const int os = jp.os[j];
    const int tid = threadIdx.x;
    const int br = blockIdx.y * 32, bc = blockIdx.x * 32;
    const int r = tid >> 3, c4 = (tid & 7) * 4;
    float4 v = *(const float4*)(in + (size_t)(br + r) * 1024 + bc + c4);
    T[r][c4 + 0] = v.x; T[r][c4 + 1] = v.y; T[r][c4 + 2] = v.z; T[r][c4 + 3] = v.w;
    __syncthreads();
    const int c = tid >> 3, r4 = (tid & 7) * 4;
    __attribute__((aligned(8))) bf16g o[4];
#pragma unroll
    for (int i = 0; i < 4; ++i) o[i] = __float2bfloat16(T[r4 + i][c]);
    *(ushort4*)(out + (size_t)(bc + c) * os + br + r4) = *(const ushort4*)o;
}

// bf16 [R rows of istride][C cols] -> bf16 [C][R]
__global__ __launch_bounds__(256) void transpose_bf16(const bf16g* __restrict__ in,
                                                      bf16g* __restrict__ out,
                                                      int R, int C, int istride) {
    __shared__ unsigned short T[32][33];
    const int tid = threadIdx.x;
    const int br = blockIdx.y * 32, bc = blockIdx.x * 32;
    const int r = tid >> 3, c4 = (tid & 7) * 4;
    ushort4 v = *(const ushort4*)((const unsigned short*)in + (size_t)(br + r) * istride + bc + c4);
    T[r][c4 + 0] = v.x; T[r][c4 + 1] = v.y; T[r][c4 + 2] = v.z; T[r][c4 + 3] = v.w;
    __syncthreads();
    const int c = tid >> 3, r4 = (tid & 7) * 4;
    ushort4 o;
    o.x = T[r4 + 0][c]; o.y = T[r4 + 1][c]; o.z = T[r4 + 2][c]; o.w = T[r4 + 3][c];
    *(ushort4*)((unsigned short*)out + (size_t)(bc + c) * R + br + r4) = o;
}

__global__ __launch_bounds__(256) void make_bias(const int* __restrict__ amask, float* __restrict__ bias) {
    const int t = blockIdx.x * 256 + threadIdx.x;
    if (t < SEQ) bias[t] = (amask[t] != 0) ? 0.f : -1e30f;
}

// ------------------- bf16 MFMA GEMM, 2-phase pipelined -------------------
// C[M,N] = A[M,K] @ BT[N,K]^T.  MODE 0: bf16 out; 1: f32 out
template <int MODE>
__global__ __launch_bounds__(256) void gemm_bf16(const bf16g* __restrict__ A,
                                                 const bf16g* __restrict__ BT,
                                                 float* __restrict__ Cf, bf16g* __restrict__ Cb,
                                                 int M, int N, int K) {
    __shared__ char As[2][16384];
    __shared__ char Bs[2][16384];
    const int tid = threadIdx.x, lane = tid & 63, w = tid >> 6;
    const int wr = (w >> 1) * 64, wc = (w & 1) * 64;
    const int bm = blockIdx.y * 128, bn = blockIdx.x * 128;
    const int l15 = lane & 15, l4 = lane >> 4;
    f32x4 z = {0.f, 0.f, 0.f, 0.f};
    f32x4 acc[4][4];
#pragma unroll
    for (int m = 0; m < 4; ++m)
#pragma unroll
        for (int n = 0; n < 4; ++n) acc[m][n] = z;

    stage128(As[0], A + (size_t)bm * K, K, tid);
    stage128(Bs[0], BT + (size_t)bn * K, K, tid);
    __syncthreads();
    int cur = 0;
    for (int k0 = 0; k0 < K; k0 += 64) {
        if (k0 + 64 < K) {
            stage128(As[cur ^ 1], A + (size_t)bm * K + k0 + 64, K, tid);
            stage128(Bs[cur ^ 1], BT + (size_t)bn * K + k0 + 64, K, tid);
        }
#pragma unroll
        for (int kk = 0; kk < 2; ++kk) {
            const int kb = kk * 32 + l4 * 8;
            bf16x8 a[4], b[4];
#pragma unroll
            for (int m = 0; m < 4; ++m) a[m] = frag64(As[cur], wr + m * 16 + l15, kb);
#pragma unroll
            for (int n = 0; n < 4; ++n) b[n] = frag64(Bs[cur], wc + n * 16 + l15, kb);
#pragma unroll
            for (int m = 0; m < 4; ++m)
#pragma unroll
                for (int n = 0; n < 4; ++n)
                    acc[m][n] = __builtin_amdgcn_mfma_f32_16x16x32_bf16(a[m], b[n], acc[m][n], 0, 0, 0);
        }
        __syncthreads();
        cur ^= 1;
    }
#pragma unroll
    for (int m = 0; m < 4; ++m)
#pragma unroll
        for (int n = 0; n < 4; ++n)
#pragma unroll
            for (int r = 0; r < 4; ++r) {
                const size_t off = (size_t)(bm + wr + m * 16 + l4 * 4 + r) * N + bn + wc + n * 16 + l15;
                if (MODE == 0) Cb[off] = __float2bfloat16(acc[m][n][r]);
                else Cf[off] = acc[m][n][r];
            }
}

// ------------------- banded softmax attention (MFMA, pipelined) -------------------
__global__ __launch_bounds__(256) void win_attn_mfma(const bf16g* __restrict__ QKV,
                                                     const bf16g* __restrict__ VT,
                                                     const float* __restrict__ bias,
                                                     bf16g* __restrict__ O) {
    __shared__ char Qs[8192];
    __shared__ char Ks[2][8192];
    __shared__ char Vs[2][8192];
    __shared__ char Ps[8192];
    const int tid = threadIdx.x, lane = tid & 63, w = tid >> 6;
    const int bid = blockIdx.x;
    const int qt = (SEQ / 64 - 1) - (bid >> 4);   // heavy-first
    const int h = bid & 15;
    const int l15 = lane & 15, l4 = lane >> 4;
    char* Pw = Ps + w * 2048;
    const bf16g* Qp = QKV + (size_t)(qt * 64) * 3072 + h * 64;
    const bf16g* Kp = QKV + 1024 + h * 64;
    const bf16g* Vp = VT + (size_t)(h * 64) * SEQ;

    stage64(Qs, Qp, 3072, tid);
    stage64(Ks[0], Kp, 3072, tid);
    stage64(Vs[0], Vp, SEQ, tid);

    f32x4 zero4 = {0.f, 0.f, 0.f, 0.f};
    f32x4 acc[4];
    float m_[4], l_[4];
#pragma unroll
    for (int n = 0; n < 4; ++n) acc[n] = zero4;
#pragma unroll
    for (int r = 0; r < 4; ++r) { m_[r] = -1e30f; l_[r] = 0.f; }

    __syncthreads();
    const bf16x8 aq0 = frag64(Qs, w * 16 + l15, l4 * 8);
    const bf16x8 aq1 = frag64(Qs, w * 16 + l15, 32 + l4 * 8);
    const int ktEnd = min(SEQ / 64 - 1, qt + 4);
    int cur = 0;
    for (int kt = 0; kt <= ktEnd; ++kt) {
        if (kt < ktEnd) {
            stage64(Ks[cur ^ 1], Kp + (size_t)((kt + 1) * 64) * 3072, 3072, tid);
            stage64(Vs[cur ^ 1], Vp + (kt + 1) * 64, SEQ, tid);
        }
        f32x4 s[4];
#pragma unroll
        for (int n = 0; n < 4; ++n) {
            f32x4 t = zero4;
            t = __builtin_amdgcn_mfma_f32_16x16x32_bf16(aq0, frag64(Ks[cur], n * 16 + l15, l4 * 8), t, 0, 0, 0);
            t = __builtin_amdgcn_mfma_f32_16x16x32_bf16(aq1, frag64(Ks[cur], n * 16 + l15, 32 + l4 * 8), t, 0, 0, 0);
            s[n] = t;
        }
#pragma unroll
        for (int n = 0; n < 4; ++n) {
            const float ab = bias[kt * 64 + n * 16 + l15];
#pragma unroll
            for (int r = 0; r < 4; ++r) {
                float sc = s[n][r] * 0.125f + ab;
                if (kt == qt + 4) {
                    const int sg = qt * 64 + w * 16 + l4 * 4 + r;
                    const int tg = kt * 64 + n * 16 + l15;
                    if (tg > sg + 255) sc = -1e30f;
                }
                s[n][r] = sc;
            }
        }
        float tm[4];
#pragma unroll
        for (int r = 0; r < 4; ++r)
            tm[r] = fmaxf(fmaxf(s[0][r], s[1][r]), fmaxf(s[2][r], s[3][r]));
#pragma unroll
        for (int off = 1; off < 16; off <<= 1)
#pragma unroll
            for (int r = 0; r < 4; ++r) tm[r] = fmaxf(tm[r], __shfl_xor(tm[r], off));
        float corr[4], rs[4];
#pragma unroll
        for (int r = 0; r < 4; ++r) {
            const float mn = fmaxf(m_[r], tm[r]);
            corr[r] = __expf(m_[r] - mn);
            m_[r] = mn;
            rs[r] = 0.f;
        }
#pragma unroll
        for (int n = 0; n < 4; ++n)
#pragma unroll
            for (int r = 0; r < 4; ++r) {
                const float p = (s[n][r] > -1e29f) ? __expf(s[n][r] - m_[r]) : 0.f;
                s[n][r] = p;
                rs[r] += p;
            }
#pragma unroll
        for (int off = 1; off < 16; off <<= 1)
#pragma unroll
            for (int r = 0; r < 4; ++r) rs[r] += __shfl_xor(rs[r], off);
#pragma unroll
        for (int r = 0; r < 4; ++r) l_[r] = l_[r] * corr[r] + rs[r];
#pragma unroll
        for (int n = 0; n < 4; ++n)
#pragma unroll
            for (int r = 0; r < 4; ++r) acc[n][r] *= corr[r];
#pragma unroll
        for (int n = 0; n < 4; ++n)
#pragma unroll
            for (int r = 0; r < 4; ++r) {
                const int prow = l4 * 4 + r;
                const int pcol = n * 16 + l15;
                const int ch = pcol >> 3;
                *(bf16g*)(Pw + prow * 128 + ((ch ^ (prow & 7)) << 4) + (pcol & 7) * 2) =
                    __float2bfloat16(s[n][r]);
            }
#pragma unroll
        for (int kk = 0; kk < 2; ++kk) {
            bf16x8 pa = frag64(Pw, l15, kk * 32 + l4 * 8);
#pragma unroll
            for (int n = 0; n < 4; ++n)
                acc[n] = __builtin_amdgcn_mfma_f32_16x16x32_bf16(
                    pa, frag64(Vs[cur], n * 16 + l15, kk * 32 + l4 * 8), acc[n], 0, 0, 0);
        }
        __syncthreads();
        cur ^= 1;
    }
#pragma unroll
    for (int n = 0; n < 4; ++n)
#pragma unroll
        for (int r = 0; r < 4; ++r) {
            const int sg = qt * 64 + w * 16 + l4 * 4 + r;
            O[(size_t)sg * 2048 + h * 64 + n * 16 + l15] = __float2bfloat16(acc[n][r] / l_[r]);
        }
}

// ------------------- linear (Taylor) attention (MFMA, pipelined) -------------------
__global__ __launch_bounds__(256) void lin_attn_mfma(const bf16g* __restrict__ QKV,
                                                     const bf16g* __restrict__ VT,
                                                     bf16g* __restrict__ O) {
    __shared__ char Qs[4096];
    __shared__ char Ks[2][4096];
    __shared__ char Vs[2][8192];
    __shared__ char Ps[8192];
    const int tid = threadIdx.x, lane = tid & 63, w = tid >> 6;
    const int bid = blockIdx.x;
    const int qt = (SEQ / 64 - 1) - (bid >> 4);   // heavy-first
    const int h = bid & 15;
    const int l15 = lane & 15, l4 = lane >> 4;
    char* Pw = Ps + w * 2048;
    const bf16g* Qp = QKV + (size_t)(qt * 64) * 1536 + h * FDIM;
    const bf16g* Kp = QKV + 256 + h * FDIM;
    const bf16g* Vp = VT + (size_t)(h * 64) * SEQ;

    const int row = tid >> 2, gp = tid & 3, g = gp ^ (row & 3);
    const uint4 z4 = {0u, 0u, 0u, 0u};
    {
        uint4 qv = (g < 2) ? *(const uint4*)(Qp + (size_t)row * 1536 + g * 8) : z4;
        *(uint4*)(Qs + row * 64 + gp * 16) = qv;
        uint4 kv = (g < 2) ? *(const uint4*)(Kp + (size_t)row * 1536 + g * 8) : z4;
        *(uint4*)(Ks[0] + row * 64 + gp * 16) = kv;
    }
    stage64(Vs[0], Vp, SEQ, tid);

    f32x4 zero4 = {0.f, 0.f, 0.f, 0.f};
    f32x4 acc[4];
    float den[4] = {0.f, 0.f, 0.f, 0.f};
#pragma unroll
    for (int n = 0; n < 4; ++n) acc[n] = zero4;

    __syncthreads();
    const bf16x8 aq = frag32(Qs, w * 16 + l15, l4 * 8);
    int cur = 0;
    for (int kt = 0; kt <= qt; ++kt) {
        uint4 knext = z4;
        if (kt < qt) {
            knext = (g < 2) ? *(const uint4*)(Kp + (size_t)((kt + 1) * 64 + row) * 1536 + g * 8) : z4;
            stage64(Vs[cur ^ 1], Vp + (kt + 1) * 64, SEQ, tid);
        }
        f32x4 s[4];
#pragma unroll
        for (int n = 0; n < 4; ++n)
            s[n] = __builtin_amdgcn_mfma_f32_16x16x32_bf16(aq, frag32(Ks[cur], n * 16 + l15, l4 * 8), zero4, 0, 0, 0);
        float rs[4] = {0.f, 0.f, 0.f, 0.f};
#pragma unroll
        for (int n = 0; n < 4; ++n)
#pragma unroll
            for (int r = 0; r < 4; ++r) {
                const float d = s[n][r];
                float sc = 1.f + 0.25f * d + d * d * (1.f / 32.f);
                if (kt == qt) {
                    const int sg = w * 16 + l4 * 4 + r;
                    const int tg = n * 16 + l15;
                    if (tg > sg) sc = 0.f;
                }
                s[n][r] = sc;
                rs[r] += sc;
            }
#pragma unroll
        for (int off = 1; off < 16; off <<= 1)
#pragma unroll
            for (int r = 0; r < 4; ++r) rs[r] += __shfl_xor(rs[r], off);
#pragma unroll
        for (int r = 0; r < 4; ++r) den[r] += rs[r];
#pragma unroll
        for (int n = 0; n < 4; ++n)
#pragma unroll
            for (int r = 0; r < 4; ++r) {
                const int prow = l4 * 4 + r;
                const int pcol = n * 16 + l15;
                const int ch = pcol >> 3;
                *(bf16g*)(Pw + prow * 128 + ((ch ^ (prow & 7)) << 4) + (pcol & 7) * 2) =
                    __float2bfloat16(s[n][r]);
            }
#pragma unroll
        for (int kk = 0; kk < 2; ++kk) {
            bf16x8 pa = frag64(Pw, l15, kk * 32 + l4 * 8);
#pragma unroll
            for (int n = 0; n < 4; ++n)
                acc[n] = __builtin_amdgcn_mfma_f32_16x16x32_bf16(
                    pa, frag64(Vs[cur], n * 16 + l15, kk * 32 + l4 * 8), acc[n], 0, 0, 0);
        }
        if (kt < qt) *(uint4*)(Ks[cur ^ 1] + row * 64 + gp * 16) = knext;
        __syncthreads();
        cur ^= 1;
    }
#pragma unroll
    for (int n = 0; n < 4; ++n)
#pragma unroll
        for (int r = 0; r < 4; ++r) {
            const int sg = qt * 64 + w * 16 + l4 * 4 + r;
            O[(size_t)sg * 2048 + h * 64 + n * 16 + l15] =
                __float2bfloat16(acc[n][r] / (den[r] + 1e-9f));
        }
}

// ------------------- host -------------------
extern "C" void kernel_launch(void* const* d_in, const int* in_sizes, int n_in,
                              void* d_out, int out_size, void* d_ws, size_t ws_size,
                              hipStream_t stream) {
    const float* h      = (const float*)d_in[0];
    const int*   amask  = (const int*)d_in[1];
    const float* lin_Wq = (const float*)d_in[2];
    const float* lin_Wk = (const float*)d_in[3];
    const float* lin_Wv = (const float*)d_in[4];
    const float* lin_Wo = (const float*)d_in[5];
    const float* win_Wq = (const float*)d_in[6];
    const float* win_Wk = (const float*)d_in[7];
    const float* win_Wv = (const float*)d_in[8];
    const float* win_Wo = (const float*)d_in[9];
    float* out = (float*)d_out;

    char* p = (char*)d_ws;
    bf16g* h_b     = (bf16g*)p; p += (size_t)SEQ * DIM * 2;
    bf16g* Blin    = (bf16g*)p; p += (size_t)1536 * DIM * 2;   // [WqlT;WklT;WvlT]
    bf16g* Bwin    = (bf16g*)p; p += (size_t)3072 * DIM * 2;   // [WqwT;WkwT;WvwT]
    bf16g* WoT     = (bf16g*)p; p += (size_t)DIM * 2048 * 2;   // [N=1024][K=2048]
    bf16g* lin_qkv = (bf16g*)p; p += (size_t)SEQ * 1536 * 2;
    bf16g* win_qkv = (bf16g*)p; p += (size_t)SEQ * 3072 * 2;
    bf16g* vlinT   = (bf16g*)p; p += (size_t)DIM * SEQ * 2;
    bf16g* vwT     = (bf16g*)p; p += (size_t)DIM * SEQ * 2;
    bf16g* att     = (bf16g*)p; p += (size_t)SEQ * 2048 * 2;   // [latt | watt]
    float* bias    = (float*)p; p += (size_t)SEQ * 4;

    const dim3 blk(256);
    convert_h<<<dim3(SEQ * DIM / 8 / 256), blk, 0, stream>>>(h, h_b);

    // two small lin projections (1024x256)
    transpose_f32_bf16<<<dim3(8, 32), blk, 0, stream>>>(lin_Wq, Blin, DIM, 256, DIM);
    transpose_f32_bf16<<<dim3(8, 32), blk, 0, stream>>>(lin_Wk, Blin + (size_t)256 * DIM, DIM, 256, DIM);
    // six square transposes batched
    TP6 jobs;
    jobs.src[0] = lin_Wv; jobs.dst[0] = Blin + (size_t)512 * DIM;  jobs.os[0] = DIM;
    jobs.src[1] = win_Wq; jobs.dst[1] = Bwin;                      jobs.os[1] = DIM;
    jobs.src[2] = win_Wk; jobs.dst[2] = Bwin + (size_t)1024 * DIM; jobs.os[2] = DIM;
    jobs.src[3] = win_Wv; jobs.dst[3] = Bwin + (size_t)2048 * DIM; jobs.os[3] = DIM;
    jobs.src[4] = lin_Wo; jobs.dst[4] = WoT;                       jobs.os[4] = 2048;
    jobs.src[5] = win_Wo; jobs.dst[5] = WoT + 1024;                jobs.os[5] = 2048;
    transpose6<<<dim3(32, 32, 6), blk, 0, stream>>>(jobs);
    make_bias<<<dim3(SEQ / 256), blk, 0, stream>>>(amask, bias);

    // fused projection GEMMs
    gemm_bf16<0><<<dim3(1536 / 128, SEQ / 128), blk, 0, stream>>>(h_b, Blin, nullptr, lin_qkv, SEQ, 1536, DIM);
    gemm_bf16<0><<<dim3(3072 / 128, SEQ / 128), blk, 0, stream>>>(h_b, Bwin, nullptr, win_qkv, SEQ, 3072, DIM);

    // V transposes (from fused qkv buffers)
    transpose_bf16<<<dim3(32, 64), blk, 0, stream>>>(lin_qkv + 512, vlinT, SEQ, DIM, 1536);
    transpose_bf16<<<dim3(32, 64), blk, 0, stream>>>(win_qkv + 2048, vwT, SEQ, DIM, 3072);

    lin_attn_mfma<<<dim3(SEQ / 64 * NH), blk, 0, stream>>>(lin_qkv, vlinT, att);
    win_attn_mfma<<<dim3(SEQ / 64 * NH), blk, 0, stream>>>(win_qkv, vwT, bias, att + 1024);

    // fused output GEMM: out = [latt|watt] @ [Wo_l; Wo_w]
    gemm_bf16<1><<<dim3(DIM / 128, SEQ / 128), blk, 0, stream>>>(att, WoT, out, nullptr, SEQ, DIM, 2048);
}

// Round 5
// 150.937 us; speedup vs baseline: 10.9756x; 1.2901x over previous
//
#include <hip/hip_runtime.h>
#include <hip/hip_bf16.h>
#include <math.h>

#define SEQ 2048
#define DIM 1024
#define NH 16
#define FDIM 16

typedef __bf16 bf16x8 __attribute__((ext_vector_type(8)));
typedef float f32x4 __attribute__((ext_vector_type(4)));
typedef __hip_bfloat16 bf16g;

__device__ __forceinline__ void gld16(const void* g, void* l) {
    __builtin_amdgcn_global_load_lds((const __attribute__((address_space(1))) void*)g,
                                     (__attribute__((address_space(3))) void*)l, 16, 0, 0);
}

// Stage a 64x64 bf16 tile (8KB) into LDS with 16B-chunk XOR swizzle.
__device__ __forceinline__ void stage64(char* lds, const bf16g* src, int stride, int tid) {
#pragma unroll
    for (int c = 0; c < 2; ++c) {
        const int idx = ((tid >> 6) * 128) + c * 64 + (tid & 63);
        const int row = idx >> 3, gg = idx & 7;
        const bf16g* gp = src + (size_t)row * stride + ((gg ^ (row & 7)) * 8);
        char* lp = lds + (((tid >> 6) * 128) + c * 64) * 16;
        gld16(gp, lp);
    }
}

// Stage a 128x64 bf16 tile (16KB).
__device__ __forceinline__ void stage128(char* lds, const bf16g* src, int stride, int tid) {
#pragma unroll
    for (int c = 0; c < 4; ++c) {
        const int idx = ((tid >> 6) * 256) + c * 64 + (tid & 63);
        const int row = idx >> 3, gg = idx & 7;
        const bf16g* gp = src + (size_t)row * stride + ((gg ^ (row & 7)) * 8);
        char* lp = lds + (((tid >> 6) * 256) + c * 64) * 16;
        gld16(gp, lp);
    }
}

__device__ __forceinline__ bf16x8 frag64(const char* lds, int row, int kbase) {
    const int ch = kbase >> 3;
    return *(const bf16x8*)(lds + row * 128 + ((ch ^ (row & 7)) << 4));
}
__device__ __forceinline__ bf16x8 frag32(const char* lds, int row, int kbase) {
    const int ch = kbase >> 3;
    return *(const bf16x8*)(lds + row * 64 + ((ch ^ (row & 3)) << 4));
}

// ------------------- prep kernels -------------------
__global__ __launch_bounds__(256) void convert_h(const float* __restrict__ in, bf16g* __restrict__ out) {
    const size_t base = ((size_t)blockIdx.x * 256 + threadIdx.x) * 8;
    float4 a = *(const float4*)(in + base);
    float4 b = *(const float4*)(in + base + 4);
    __attribute__((aligned(16))) bf16g t[8];
    t[0] = __float2bfloat16(a.x); t[1] = __float2bfloat16(a.y);
    t[2] = __float2bfloat16(a.z); t[3] = __float2bfloat16(a.w);
    t[4] = __float2bfloat16(b.x); t[5] = __float2bfloat16(b.y);
    t[6] = __float2bfloat16(b.z); t[7] = __float2bfloat16(b.w);
    *(uint4*)(out + base) = *(const uint4*)t;
}

// f32 [R][C] -> bf16 [C][ostride]
__global__ __launch_bounds__(256) void transpose_f32_bf16(const float* __restrict__ in,
                                                          bf16g* __restrict__ out,
                                                          int R, int C, int ostride) {
    __shared__ float T[32][33];
    const int tid = threadIdx.x;
    const int br = blockIdx.y * 32, bc = blockIdx.x * 32;
    const int r = tid >> 3, c4 = (tid & 7) * 4;
    float4 v = *(const float4*)(in + (size_t)(br + r) * C + bc + c4);
    T[r][c4 + 0] = v.x; T[r][c4 + 1] = v.y; T[r][c4 + 2] = v.z; T[r][c4 + 3] = v.w;
    __syncthreads();
    const int c = tid >> 3, r4 = (tid & 7) * 4;
    __attribute__((aligned(8))) bf16g o[4];
#pragma unroll
    for (int i = 0; i < 4; ++i) o[i] = __float2bfloat16(T[r4 + i][c]);
    *(ushort4*)(out + (size_t)(bc + c) * ostride + br + r4) = *(const ushort4*)o;
}

struct TP6 { const float* src[6]; bf16g* dst[6]; int os[6]; };
__global__ __launch_bounds__(256) void transpose6(TP6 jp) {
    __shared__ float T[32][33];
    const int j = blockIdx.z;
    const float* in = jp.src[j];
    bf16g* out = jp.dst[j];
    const int os = jp.os[j];
    const int tid = threadIdx.x;
    const int br = blockIdx.y * 32, bc = blockIdx.x * 32;
    const int r = tid >> 3, c4 = (tid & 7) * 4;
    float4 v = *(const float4*)(in + (size_t)(br + r) * 1024 + bc + c4);
    T[r][c4 + 0] = v.x; T[r][c4 + 1] = v.y; T[r][c4 + 2] = v.z; T[r][c4 + 3] = v.w;
    __syncthreads();
    const int c = tid >> 3, r4 = (tid & 7) * 4;
    __attribute__((aligned(8))) bf16g o[4];
#pragma unroll
    for (int i = 0; i < 4; ++i) o[i] = __float2bfloat16(T[r4 + i][c]);
    *(ushort4*)(out + (size_t)(bc + c) * os + br + r4) = *(const ushort4*)o;
}

__global__ __launch_bounds__(256) void transpose_bf16(const bf16g* __restrict__ in,
                                                      bf16g* __restrict__ out,
                                                      int R, int C, int istride) {
    __shared__ unsigned short T[32][33];
    const int tid = threadIdx.x;
    const int br = blockIdx.y * 32, bc = blockIdx.x * 32;
    const int r = tid >> 3, c4 = (tid & 7) * 4;
    ushort4 v = *(const ushort4*)((const unsigned short*)in + (size_t)(br + r) * istride + bc + c4);
    T[r][c4 + 0] = v.x; T[r][c4 + 1] = v.y; T[r][c4 + 2] = v.z; T[r][c4 + 3] = v.w;
    __syncthreads();
    const int c = tid >> 3, r4 = (tid & 7) * 4;
    ushort4 o;
    o.x = T[r4 + 0][c]; o.y = T[r4 + 1][c]; o.z = T[r4 + 2][c]; o.w = T[r4 + 3][c];
    *(ushort4*)((unsigned short*)out + (size_t)(bc + c) * R + br + r4) = o;
}

__global__ __launch_bounds__(256) void make_bias(const int* __restrict__ amask, float* __restrict__ bias) {
    const int t = blockIdx.x * 256 + threadIdx.x;
    if (t < SEQ) bias[t] = (amask[t] != 0) ? 0.f : -1e30f;
}

// ------------------- bf16 MFMA GEMM, 2-phase pipelined -------------------
template <int MODE>
__global__ __launch_bounds__(256) void gemm_bf16(const bf16g* __restrict__ A,
                                                 const bf16g* __restrict__ BT,
                                                 float* __restrict__ Cf, bf16g* __restrict__ Cb,
                                                 int M, int N, int K) {
    __shared__ char As[2][16384];
    __shared__ char Bs[2][16384];
    const int tid = threadIdx.x, lane = tid & 63, w = tid >> 6;
    const int wr = (w >> 1) * 64, wc = (w & 1) * 64;
    const int bm = blockIdx.y * 128, bn = blockIdx.x * 128;
    const int l15 = lane & 15, l4 = lane >> 4;
    f32x4 z = {0.f, 0.f, 0.f, 0.f};
    f32x4 acc[4][4];
#pragma unroll
    for (int m = 0; m < 4; ++m)
#pragma unroll
        for (int n = 0; n < 4; ++n) acc[m][n] = z;

    stage128(As[0], A + (size_t)bm * K, K, tid);
    stage128(Bs[0], BT + (size_t)bn * K, K, tid);
    __syncthreads();
    int cur = 0;
    for (int k0 = 0; k0 < K; k0 += 64) {
        if (k0 + 64 < K) {
            stage128(As[cur ^ 1], A + (size_t)bm * K + k0 + 64, K, tid);
            stage128(Bs[cur ^ 1], BT + (size_t)bn * K + k0 + 64, K, tid);
        }
#pragma unroll
        for (int kk = 0; kk < 2; ++kk) {
            const int kb = kk * 32 + l4 * 8;
            bf16x8 a[4], b[4];
#pragma unroll
            for (int m = 0; m < 4; ++m) a[m] = frag64(As[cur], wr + m * 16 + l15, kb);
#pragma unroll
            for (int n = 0; n < 4; ++n) b[n] = frag64(Bs[cur], wc + n * 16 + l15, kb);
#pragma unroll
            for (int m = 0; m < 4; ++m)
#pragma unroll
                for (int n = 0; n < 4; ++n)
                    acc[m][n] = __builtin_amdgcn_mfma_f32_16x16x32_bf16(a[m], b[n], acc[m][n], 0, 0, 0);
        }
        __syncthreads();
        cur ^= 1;
    }
#pragma unroll
    for (int m = 0; m < 4; ++m)
#pragma unroll
        for (int n = 0; n < 4; ++n)
#pragma unroll
            for (int r = 0; r < 4; ++r) {
                const size_t off = (size_t)(bm + wr + m * 16 + l4 * 4 + r) * N + bn + wc + n * 16 + l15;
                if (MODE == 0) Cb[off] = __float2bfloat16(acc[m][n][r]);
                else Cf[off] = acc[m][n][r];
            }
}

// ------------------- fused attention (win + lin), shuffle-free softmax ------
__global__ __launch_bounds__(256) void attn_fused(const bf16g* __restrict__ lin_qkv,
                                                  const bf16g* __restrict__ vlinT,
                                                  const bf16g* __restrict__ win_qkv,
                                                  const bf16g* __restrict__ vwT,
                                                  const float* __restrict__ bias,
                                                  bf16g* __restrict__ att) {
    __shared__ char L[49152];
    const int tid = threadIdx.x, lane = tid & 63, w = tid >> 6;
    const int bid = blockIdx.x;
    const int idx = bid >> 1;
    const int qt = (SEQ / 64 - 1) - (idx >> 4);   // heavy-first
    const int h = idx & 15;
    const int l15 = lane & 15, l4 = lane >> 4;
    char* Pw = L + 40960 + w * 2048;

    bf16x8 vones;
#pragma unroll
    for (int i = 0; i < 8; ++i) vones[i] = (__bf16)1.0f;
    const f32x4 zero4 = {0.f, 0.f, 0.f, 0.f};
    f32x4 acc[4], accl = zero4;
#pragma unroll
    for (int n = 0; n < 4; ++n) acc[n] = zero4;

    if ((bid & 1) == 0) {
        // ---------------- win branch ----------------
        // LDS: Qs@0, K buffers @8192+cur*8192, V buffers @24576+cur*8192
        const bf16g* Qp = win_qkv + (size_t)(qt * 64) * 3072 + h * 64;
        const bf16g* Kp = win_qkv + 1024 + h * 64;
        const bf16g* Vp = vwT + (size_t)(h * 64) * SEQ;

        stage64(L, Qp, 3072, tid);
        stage64(L + 8192, Kp, 3072, tid);
        stage64(L + 24576, Vp, SEQ, tid);
        __syncthreads();
        const bf16x8 aq0 = frag64(L, w * 16 + l15, l4 * 8);
        const bf16x8 aq1 = frag64(L, w * 16 + l15, 32 + l4 * 8);
        const int ktEnd = min(SEQ / 64 - 1, qt + 4);
        int cur = 0;
        for (int kt = 0; kt <= ktEnd; ++kt) {
            const int kOff = 8192 + cur * 8192;
            const int vOff = 24576 + cur * 8192;
            if (kt < ktEnd) {
                stage64(L + (8192 + (cur ^ 1) * 8192), Kp + (size_t)((kt + 1) * 64) * 3072, 3072, tid);
                stage64(L + (24576 + (cur ^ 1) * 8192), Vp + (kt + 1) * 64, SEQ, tid);
            }
            f32x4 s[4];
#pragma unroll
            for (int n = 0; n < 4; ++n) {
                f32x4 t = zero4;
                t = __builtin_amdgcn_mfma_f32_16x16x32_bf16(aq0, frag64(L + kOff, n * 16 + l15, l4 * 8), t, 0, 0, 0);
                t = __builtin_amdgcn_mfma_f32_16x16x32_bf16(aq1, frag64(L + kOff, n * 16 + l15, 32 + l4 * 8), t, 0, 0, 0);
                s[n] = t;
            }
            // scale + bias + band mask + exp (fixed shift -3; no online max)
#pragma unroll
            for (int n = 0; n < 4; ++n) {
                const float ab = bias[kt * 64 + n * 16 + l15] - 3.0f;
#pragma unroll
                for (int r = 0; r < 4; ++r) {
                    float sc = s[n][r] * 0.125f + ab;
                    if (kt == qt + 4) {
                        const int sg = qt * 64 + w * 16 + l4 * 4 + r;
                        const int tg = kt * 64 + n * 16 + l15;
                        if (tg > sg + 255) sc = -1e30f;
                    }
                    const float p = __expf(sc);
                    const int prow = l4 * 4 + r;
                    const int pcol = n * 16 + l15;
                    const int ch = pcol >> 3;
                    *(bf16g*)(Pw + prow * 128 + ((ch ^ (prow & 7)) << 4) + (pcol & 7) * 2) =
                        __float2bfloat16(p);
                }
            }
#pragma unroll
            for (int kk = 0; kk < 2; ++kk) {
                bf16x8 pa = frag64(Pw, l15, kk * 32 + l4 * 8);
#pragma unroll
                for (int n = 0; n < 4; ++n)
                    acc[n] = __builtin_amdgcn_mfma_f32_16x16x32_bf16(
                        pa, frag64(L + vOff, n * 16 + l15, kk * 32 + l4 * 8), acc[n], 0, 0, 0);
                accl = __builtin_amdgcn_mfma_f32_16x16x32_bf16(pa, vones, accl, 0, 0, 0);
            }
            __syncthreads();
            cur ^= 1;
        }
#pragma unroll
        for (int n = 0; n < 4; ++n)
#pragma unroll
            for (int r = 0; r < 4; ++r) {
                const int sg = qt * 64 + w * 16 + l4 * 4 + r;
                att[(size_t)sg * 2048 + 1024 + h * 64 + n * 16 + l15] =
                    __float2bfloat16(acc[n][r] / accl[r]);
            }
    } else {
        // ---------------- lin branch ----------------
        // LDS: Qs@0 (4KB), K buffers @4096+cur*4096, V buffers @24576+cur*8192
        const bf16g* Qp = lin_qkv + (size_t)(qt * 64) * 1536 + h * FDIM;
        const bf16g* Kp = lin_qkv + 256 + h * FDIM;
        const bf16g* Vp = vlinT + (size_t)(h * 64) * SEQ;

        const int row = tid >> 2, gp = tid & 3, g = gp ^ (row & 3);
        const uint4 z4 = {0u, 0u, 0u, 0u};
        {
            uint4 qv = (g < 2) ? *(const uint4*)(Qp + (size_t)row * 1536 + g * 8) : z4;
            *(uint4*)(L + row * 64 + gp * 16) = qv;
            uint4 kv = (g < 2) ? *(const uint4*)(Kp + (size_t)row * 1536 + g * 8) : z4;
            *(uint4*)(L + 4096 + row * 64 + gp * 16) = kv;
        }
        stage64(L + 24576, Vp, SEQ, tid);
        __syncthreads();
        const bf16x8 aq = frag32(L, w * 16 + l15, l4 * 8);
        int cur = 0;
        for (int kt = 0; kt <= qt; ++kt) {
            const int kOff = 4096 + cur * 4096;
            const int vOff = 24576 + cur * 8192;
            uint4 knext = z4;
            if (kt < qt) {
                knext = (g < 2) ? *(const uint4*)(Kp + (size_t)((kt + 1) * 64 + row) * 1536 + g * 8) : z4;
                stage64(L + (24576 + (cur ^ 1) * 8192), Vp + (kt + 1) * 64, SEQ, tid);
            }
            f32x4 s[4];
#pragma unroll
            for (int n = 0; n < 4; ++n)
                s[n] = __builtin_amdgcn_mfma_f32_16x16x32_bf16(aq, frag32(L + kOff, n * 16 + l15, l4 * 8), zero4, 0, 0, 0);
#pragma unroll
            for (int n = 0; n < 4; ++n)
#pragma unroll
                for (int r = 0; r < 4; ++r) {
                    const float d = s[n][r];
                    float sc = 1.f + 0.25f * d + d * d * (1.f / 32.f);
                    if (kt == qt) {
                        const int sg = w * 16 + l4 * 4 + r;
                        const int tg = n * 16 + l15;
                        if (tg > sg) sc = 0.f;
                    }
                    const int prow = l4 * 4 + r;
                    const int pcol = n * 16 + l15;
                    const int ch = pcol >> 3;
                    *(bf16g*)(Pw + prow * 128 + ((ch ^ (prow & 7)) << 4) + (pcol & 7) * 2) =
                        __float2bfloat16(sc);
                }
#pragma unroll
            for (int kk = 0; kk < 2; ++kk) {
                bf16x8 pa = frag64(Pw, l15, kk * 32 + l4 * 8);
#pragma unroll
                for (int n = 0; n < 4; ++n)
                    acc[n] = __builtin_amdgcn_mfma_f32_16x16x32_bf16(
                        pa, frag64(L + vOff, n * 16 + l15, kk * 32 + l4 * 8), acc[n], 0, 0, 0);
                accl = __builtin_amdgcn_mfma_f32_16x16x32_bf16(pa, vones, accl, 0, 0, 0);
            }
            if (kt < qt) *(uint4*)(L + (4096 + (cur ^ 1) * 4096) + row * 64 + gp * 16) = knext;
            __syncthreads();
            cur ^= 1;
        }
#pragma unroll
        for (int n = 0; n < 4; ++n)
#pragma unroll
            for (int r = 0; r < 4; ++r) {
                const int sg = qt * 64 + w * 16 + l4 * 4 + r;
                att[(size_t)sg * 2048 + h * 64 + n * 16 + l15] =
                    __float2bfloat16(acc[n][r] / (accl[r] + 1e-9f));
            }
    }
}

// ------------------- host -------------------
extern "C" void kernel_launch(void* const* d_in, const int* in_sizes, int n_in,
                              void* d_out, int out_size, void* d_ws, size_t ws_size,
                              hipStream_t stream) {
    const float* h      = (const float*)d_in[0];
    const int*   amask  = (const int*)d_in[1];
    const float* lin_Wq = (const float*)d_in[2];
    const float* lin_Wk = (const float*)d_in[3];
    const float* lin_Wv = (const float*)d_in[4];
    const float* lin_Wo = (const float*)d_in[5];
    const float* win_Wq = (const float*)d_in[6];
    const float* win_Wk = (const float*)d_in[7];
    const float* win_Wv = (const float*)d_in[8];
    const float* win_Wo = (const float*)d_in[9];
    float* out = (float*)d_out;

    char* p = (char*)d_ws;
    bf16g* h_b     = (bf16g*)p; p += (size_t)SEQ * DIM * 2;
    bf16g* Blin    = (bf16g*)p; p += (size_t)1536 * DIM * 2;
    bf16g* Bwin    = (bf16g*)p; p += (size_t)3072 * DIM * 2;
    bf16g* WoT     = (bf16g*)p; p += (size_t)DIM * 2048 * 2;
    bf16g* lin_qkv = (bf16g*)p; p += (size_t)SEQ * 1536 * 2;
    bf16g* win_qkv = (bf16g*)p; p += (size_t)SEQ * 3072 * 2;
    bf16g* vlinT   = (bf16g*)p; p += (size_t)DIM * SEQ * 2;
    bf16g* vwT     = (bf16g*)p; p += (size_t)DIM * SEQ * 2;
    bf16g* att     = (bf16g*)p; p += (size_t)SEQ * 2048 * 2;
    float* bias    = (float*)p; p += (size_t)SEQ * 4;

    const dim3 blk(256);
    convert_h<<<dim3(SEQ * DIM / 8 / 256), blk, 0, stream>>>(h, h_b);

    transpose_f32_bf16<<<dim3(8, 32), blk, 0, stream>>>(lin_Wq, Blin, DIM, 256, DIM);
    transpose_f32_bf16<<<dim3(8, 32), blk, 0, stream>>>(lin_Wk, Blin + (size_t)256 * DIM, DIM, 256, DIM);
    TP6 jobs;
    jobs.src[0] = lin_Wv; jobs.dst[0] = Blin + (size_t)512 * DIM;  jobs.os[0] = DIM;
    jobs.src[1] = win_Wq; jobs.dst[1] = Bwin;                      jobs.os[1] = DIM;
    jobs.src[2] = win_Wk; jobs.dst[2] = Bwin + (size_t)1024 * DIM; jobs.os[2] = DIM;
    jobs.src[3] = win_Wv; jobs.dst[3] = Bwin + (size_t)2048 * DIM; jobs.os[3] = DIM;
    jobs.src[4] = lin_Wo; jobs.dst[4] = WoT;                       jobs.os[4] = 2048;
    jobs.src[5] = win_Wo; jobs.dst[5] = WoT + 1024;                jobs.os[5] = 2048;
    transpose6<<<dim3(32, 32, 6), blk, 0, stream>>>(jobs);
    make_bias<<<dim3(SEQ / 256), blk, 0, stream>>>(amask, bias);

    gemm_bf16<0><<<dim3(1536 / 128, SEQ / 128), blk, 0, stream>>>(h_b, Blin, nullptr, lin_qkv, SEQ, 1536, DIM);
    gemm_bf16<0><<<dim3(3072 / 128, SEQ / 128), blk, 0, stream>>>(h_b, Bwin, nullptr, win_qkv, SEQ, 3072, DIM);

    transpose_bf16<<<dim3(32, 64), blk, 0, stream>>>(lin_qkv + 512, vlinT, SEQ, DIM, 1536);
    transpose_bf16<<<dim3(32, 64), blk, 0, stream>>>(win_qkv + 2048, vwT, SEQ, DIM, 3072);

    attn_fused<<<dim3(2 * SEQ / 64 * NH), blk, 0, stream>>>(lin_qkv, vlinT, win_qkv, vwT, bias, att);

    gemm_bf16<1><<<dim3(DIM / 128, SEQ / 128), blk, 0, stream>>>(att, WoT, out, nullptr, SEQ, DIM, 2048);
}

// Round 6
// 144.715 us; speedup vs baseline: 11.4475x; 1.0430x over previous
//
#include <hip/hip_runtime.h>
#include <hip/hip_bf16.h>
#include <math.h>

#define SEQ 2048
#define DIM 1024
#define NH 16
#define FDIM 16
#define QS 4608   // fused qkv row stride

typedef __bf16 bf16x8 __attribute__((ext_vector_type(8)));
typedef float f32x4 __attribute__((ext_vector_type(4)));
typedef __hip_bfloat16 bf16g;

__device__ __forceinline__ void gld16(const void* g, void* l) {
    __builtin_amdgcn_global_load_lds((const __attribute__((address_space(1))) void*)g,
                                     (__attribute__((address_space(3))) void*)l, 16, 0, 0);
}

// ---- 256-thread stagers (GEMM) ----
__device__ __forceinline__ void stage128(char* lds, const bf16g* src, int stride, int tid) {
#pragma unroll
    for (int c = 0; c < 4; ++c) {
        const int idx = ((tid >> 6) * 256) + c * 64 + (tid & 63);
        const int row = idx >> 3, gg = idx & 7;
        gld16(src + (size_t)row * stride + ((gg ^ (row & 7)) * 8), lds + idx * 16);
    }
}
// ---- 512-thread stagers (attn) ----
__device__ __forceinline__ void stage64_512(char* lds, const bf16g* src, int stride, int tid) {
    const int row = tid >> 3, gg = tid & 7;
    gld16(src + (size_t)row * stride + ((gg ^ (row & 7)) * 8), lds + tid * 16);
}
__device__ __forceinline__ void stage128_512(char* lds, const bf16g* src, int stride, int tid) {
#pragma unroll
    for (int c = 0; c < 2; ++c) {
        const int idx = c * 512 + tid;
        const int row = idx >> 3, gg = idx & 7;
        gld16(src + (size_t)row * stride + ((gg ^ (row & 7)) * 8), lds + idx * 16);
    }
}

__device__ __forceinline__ bf16x8 frag64(const char* lds, int row, int kbase) {
    const int ch = kbase >> 3;
    return *(const bf16x8*)(lds + row * 128 + ((ch ^ (row & 7)) << 4));
}
__device__ __forceinline__ bf16x8 frag32(const char* lds, int row, int kbase) {
    const int ch = kbase >> 3;
    return *(const bf16x8*)(lds + row * 64 + ((ch ^ (row & 3)) << 4));
}

// ------------------- prep kernels -------------------
__global__ __launch_bounds__(256) void convert_h(const float* __restrict__ in, bf16g* __restrict__ out) {
    const size_t base = ((size_t)blockIdx.x * 256 + threadIdx.x) * 8;
    float4 a = *(const float4*)(in + base);
    float4 b = *(const float4*)(in + base + 4);
    __attribute__((aligned(16))) bf16g t[8];
    t[0] = __float2bfloat16(a.x); t[1] = __float2bfloat16(a.y);
    t[2] = __float2bfloat16(a.z); t[3] = __float2bfloat16(a.w);
    t[4] = __float2bfloat16(b.x); t[5] = __float2bfloat16(b.y);
    t[6] = __float2bfloat16(b.z); t[7] = __float2bfloat16(b.w);
    *(uint4*)(out + base) = *(const uint4*)t;
}

__global__ __launch_bounds__(256) void transpose_f32_bf16(const float* __restrict__ in,
                                                          bf16g* __restrict__ out,
                                                          int R, int C, int ostride) {
    __shared__ float T[32][33];
    const int tid = threadIdx.x;
    const int br = blockIdx.y * 32, bc = blockIdx.x * 32;
    const int r = tid >> 3, c4 = (tid & 7) * 4;
    float4 v = *(const float4*)(in + (size_t)(br + r) * C + bc + c4);
    T[r][c4 + 0] = v.x; T[r][c4 + 1] = v.y; T[r][c4 + 2] = v.z; T[r][c4 + 3] = v.w;
    __syncthreads();
    const int c = tid >> 3, r4 = (tid & 7) * 4;
    __attribute__((aligned(8))) bf16g o[4];
#pragma unroll
    for (int i = 0; i < 4; ++i) o[i] = __float2bfloat16(T[r4 + i][c]);
    *(ushort4*)(out + (size_t)(bc + c) * ostride + br + r4) = *(const ushort4*)o;
}

struct TP6 { const float* src[6]; bf16g* dst[6]; int os[6]; };
__global__ __launch_bounds__(256) void transpose6(TP6 jp) {
    __shared__ float T[32][33];
    const int j = blockIdx.z;
    const float* in = jp.src[j];
    bf16g* out = jp.dst[j];
    const int os = jp.os[j];
    const int tid = threadIdx.x;
    const int br = blockIdx.y * 32, bc = blockIdx.x * 32;
    const int r = tid >> 3, c4 = (tid & 7) * 4;
    float4 v = *(const float4*)(in + (size_t)(br + r) * 1024 + bc + c4);
    T[r][c4 + 0] = v.x; T[r][c4 + 1] = v.y; T[r][c4 + 2] = v.z; T[r][c4 + 3] = v.w;
    __syncthreads();
    const int c = tid >> 3, r4 = (tid & 7) * 4;
    __attribute__((aligned(8))) bf16g o[4];
#pragma unroll
    for (int i = 0; i < 4; ++i) o[i] = __float2bfloat16(T[r4 + i][c]);
    *(ushort4*)(out + (size_t)(bc + c) * os + br + r4) = *(const ushort4*)o;
}

// both V transposes: [2048, stride QS][1024] -> [1024][2048]
__global__ __launch_bounds__(256) void transposeV(const bf16g* __restrict__ qkv,
                                                  bf16g* __restrict__ vlinT,
                                                  bf16g* __restrict__ vwT) {
    __shared__ unsigned short T[32][33];
    const int z = blockIdx.z;
    const unsigned short* in = (const unsigned short*)(qkv + (z ? 3584 : 512));
    unsigned short* out = (unsigned short*)(z ? vwT : vlinT);
    const int tid = threadIdx.x;
    const int br = blockIdx.y * 32, bc = blockIdx.x * 32;
    const int r = tid >> 3, c4 = (tid & 7) * 4;
    ushort4 v = *(const ushort4*)(in + (size_t)(br + r) * QS + bc + c4);
    T[r][c4 + 0] = v.x; T[r][c4 + 1] = v.y; T[r][c4 + 2] = v.z; T[r][c4 + 3] = v.w;
    __syncthreads();
    const int c = tid >> 3, r4 = (tid & 7) * 4;
    ushort4 o;
    o.x = T[r4 + 0][c]; o.y = T[r4 + 1][c]; o.z = T[r4 + 2][c]; o.w = T[r4 + 3][c];
    *(ushort4*)(out + (size_t)(bc + c) * SEQ + br + r4) = o;
}

__global__ __launch_bounds__(256) void make_bias(const int* __restrict__ amask, float* __restrict__ bias) {
    const int t = blockIdx.x * 256 + threadIdx.x;
    if (t < SEQ) bias[t] = (amask[t] != 0) ? 0.f : -1e30f;
}

// ------------------- bf16 MFMA GEMM, 2-phase pipelined -------------------
template <int MODE>
__global__ __launch_bounds__(256) void gemm_bf16(const bf16g* __restrict__ A,
                                                 const bf16g* __restrict__ BT,
                                                 float* __restrict__ Cf, bf16g* __restrict__ Cb,
                                                 int M, int N, int K) {
    __shared__ char As[2][16384];
    __shared__ char Bs[2][16384];
    const int tid = threadIdx.x, lane = tid & 63, w = tid >> 6;
    const int wr = (w >> 1) * 64, wc = (w & 1) * 64;
    const int bm = blockIdx.y * 128, bn = blockIdx.x * 128;
    const int l15 = lane & 15, l4 = lane >> 4;
    f32x4 z = {0.f, 0.f, 0.f, 0.f};
    f32x4 acc[4][4];
#pragma unroll
    for (int m = 0; m < 4; ++m)
#pragma unroll
        for (int n = 0; n < 4; ++n) acc[m][n] = z;

    stage128(As[0], A + (size_t)bm * K, K, tid);
    stage128(Bs[0], BT + (size_t)bn * K, K, tid);
    __syncthreads();
    int cur = 0;
    for (int k0 = 0; k0 < K; k0 += 64) {
        if (k0 + 64 < K) {
            stage128(As[cur ^ 1], A + (size_t)bm * K + k0 + 64, K, tid);
            stage128(Bs[cur ^ 1], BT + (size_t)bn * K + k0 + 64, K, tid);
        }
#pragma unroll
        for (int kk = 0; kk < 2; ++kk) {
            const int kb = kk * 32 + l4 * 8;
            bf16x8 a[4], b[4];
#pragma unroll
            for (int m = 0; m < 4; ++m) a[m] = frag64(As[cur], wr + m * 16 + l15, kb);
#pragma unroll
            for (int n = 0; n < 4; ++n) b[n] = frag64(Bs[cur], wc + n * 16 + l15, kb);
#pragma unroll
            for (int m = 0; m < 4; ++m)
#pragma unroll
                for (int n = 0; n < 4; ++n)
                    acc[m][n] = __builtin_amdgcn_mfma_f32_16x16x32_bf16(a[m], b[n], acc[m][n], 0, 0, 0);
        }
        __syncthreads();
        cur ^= 1;
    }
#pragma unroll
    for (int m = 0; m < 4; ++m)
#pragma unroll
        for (int n = 0; n < 4; ++n)
#pragma unroll
            for (int r = 0; r < 4; ++r) {
                const size_t off = (size_t)(bm + wr + m * 16 + l4 * 4 + r) * N + bn + wc + n * 16 + l15;
                if (MODE == 0) Cb[off] = __float2bfloat16(acc[m][n][r]);
                else Cf[off] = acc[m][n][r];
            }
}

// ------------------- fused attention: 8 waves, 128 q-rows/block -------------
// LDS map (64KB): win: Q[128][64]@0(16K), K dbuf @16384+cur*8192, V dbuf @32768+cur*8192
//                 lin: Q[128][32]@0(8K),  K dbuf @16384+cur*4096, V dbuf @32768+cur*8192
//                 P: @49152 + w*2048 (16K)
__global__ __launch_bounds__(512) void attn_fused(const bf16g* __restrict__ qkv,
                                                  const bf16g* __restrict__ vlinT,
                                                  const bf16g* __restrict__ vwT,
                                                  const float* __restrict__ bias,
                                                  bf16g* __restrict__ att) {
    __shared__ char L[65536];
    const int tid = threadIdx.x, lane = tid & 63, w = tid >> 6;
    const int bid = blockIdx.x;
    const int branch = bid & 1;
    const int rest = bid >> 1;
    const int h = rest & 15;
    const int Qt = 15 - (rest >> 4);   // heavy-first
    const int l15 = lane & 15, l4 = lane >> 4;
    char* Pw = L + 49152 + w * 2048;

    bf16x8 vones;
#pragma unroll
    for (int i = 0; i < 8; ++i) vones[i] = (__bf16)1.0f;
    const f32x4 zero4 = {0.f, 0.f, 0.f, 0.f};
    f32x4 acc[4], accl = zero4;
#pragma unroll
    for (int n = 0; n < 4; ++n) acc[n] = zero4;
    const int qrow = w * 16 + l15;              // this wave's Q rows (frag row)
    const int sgBase = Qt * 128 + w * 16 + l4 * 4;  // + r = global q row of C-frag

    if (branch == 0) {
        // ---------------- win branch ----------------
        const bf16g* Qp = qkv + (size_t)(Qt * 128) * QS + 1536 + h * 64;
        const bf16g* Kp = qkv + 2560 + h * 64;
        const bf16g* Vp = vwT + (size_t)(h * 64) * SEQ;

        stage128_512(L, Qp, QS, tid);
        stage64_512(L + 16384, Kp, QS, tid);
        stage64_512(L + 32768, Vp, SEQ, tid);
        __syncthreads();
        const bf16x8 aq0 = frag64(L, qrow, l4 * 8);
        const bf16x8 aq1 = frag64(L, qrow, 32 + l4 * 8);
        const int ktEnd = min(31, 2 * Qt + 5);
        int cur = 0;
        for (int kt = 0; kt <= ktEnd; ++kt) {
            const int kOff = 16384 + cur * 8192;
            const int vOff = 32768 + cur * 8192;
            if (kt < ktEnd) {
                stage64_512(L + (16384 + (cur ^ 1) * 8192), Kp + (size_t)((kt + 1) * 64) * QS, QS, tid);
                stage64_512(L + (32768 + (cur ^ 1) * 8192), Vp + (kt + 1) * 64, SEQ, tid);
            }
            f32x4 s[4];
            __builtin_amdgcn_s_setprio(1);
#pragma unroll
            for (int n = 0; n < 4; ++n) {
                f32x4 t = zero4;
                t = __builtin_amdgcn_mfma_f32_16x16x32_bf16(aq0, frag64(L + kOff, n * 16 + l15, l4 * 8), t, 0, 0, 0);
                t = __builtin_amdgcn_mfma_f32_16x16x32_bf16(aq1, frag64(L + kOff, n * 16 + l15, 32 + l4 * 8), t, 0, 0, 0);
                s[n] = t;
            }
            __builtin_amdgcn_s_setprio(0);
            const bool needMask = (kt >= 2 * Qt + 4);
#pragma unroll
            for (int n = 0; n < 4; ++n) {
                const float ab = bias[kt * 64 + n * 16 + l15] - 3.0f;
#pragma unroll
                for (int r = 0; r < 4; ++r) {
                    float sc = s[n][r] * 0.125f + ab;
                    if (needMask) {
                        const int tg = kt * 64 + n * 16 + l15;
                        if (tg > sgBase + r + 255) sc = -1e30f;
                    }
                    const float p = __expf(sc);
                    const int prow = l4 * 4 + r;
                    const int pcol = n * 16 + l15;
                    const int ch = pcol >> 3;
                    *(bf16g*)(Pw + prow * 128 + ((ch ^ (prow & 7)) << 4) + (pcol & 7) * 2) =
                        __float2bfloat16(p);
                }
            }
            __builtin_amdgcn_s_setprio(1);
#pragma unroll
            for (int kk = 0; kk < 2; ++kk) {
                bf16x8 pa = frag64(Pw, l15, kk * 32 + l4 * 8);
#pragma unroll
                for (int n = 0; n < 4; ++n)
                    acc[n] = __builtin_amdgcn_mfma_f32_16x16x32_bf16(
                        pa, frag64(L + vOff, n * 16 + l15, kk * 32 + l4 * 8), acc[n], 0, 0, 0);
                accl = __builtin_amdgcn_mfma_f32_16x16x32_bf16(pa, vones, accl, 0, 0, 0);
            }
            __builtin_amdgcn_s_setprio(0);
            __syncthreads();
            cur ^= 1;
        }
#pragma unroll
        for (int n = 0; n < 4; ++n)
#pragma unroll
            for (int r = 0; r < 4; ++r) {
                const int sg = sgBase + r;
                att[(size_t)sg * 2048 + 1024 + h * 64 + n * 16 + l15] =
                    __float2bfloat16(acc[n][r] / accl[r]);
            }
    } else {
        // ---------------- lin branch ----------------
        const bf16g* Qp = qkv + (size_t)(Qt * 128) * QS + h * FDIM;
        const bf16g* Kp = qkv + 256 + h * FDIM;
        const bf16g* Vp = vlinT + (size_t)(h * 64) * SEQ;

        const uint4 z4 = {0u, 0u, 0u, 0u};
        {   // Q [128][32] zero-padded: 512 chunks, all threads
            const int row = tid >> 2, gp = tid & 3, g = gp ^ (row & 3);
            uint4 qv = (g < 2) ? *(const uint4*)(Qp + (size_t)row * QS + g * 8) : z4;
            *(uint4*)(L + row * 64 + gp * 16) = qv;
        }
        if (tid < 256) {   // K [64][32]: 256 chunks
            const int row = tid >> 2, gp = tid & 3, g = gp ^ (row & 3);
            uint4 kv = (g < 2) ? *(const uint4*)(Kp + (size_t)row * QS + g * 8) : z4;
            *(uint4*)(L + 16384 + row * 64 + gp * 16) = kv;
        }
        stage64_512(L + 32768, Vp, SEQ, tid);
        __syncthreads();
        const bf16x8 aq = frag32(L, qrow, l4 * 8);
        const int ktEnd = 2 * Qt + 1;
        int cur = 0;
        for (int kt = 0; kt <= ktEnd; ++kt) {
            const int kOff = 16384 + cur * 4096;
            const int vOff = 32768 + cur * 8192;
            uint4 knext = z4;
            const int row = tid >> 2, gp = tid & 3, g = gp ^ (row & 3);
            if (kt < ktEnd) {
                if (tid < 256 && g < 2)
                    knext = *(const uint4*)(Kp + (size_t)((kt + 1) * 64 + row) * QS + g * 8);
                stage64_512(L + (32768 + (cur ^ 1) * 8192), Vp + (kt + 1) * 64, SEQ, tid);
            }
            f32x4 s[4];
            __builtin_amdgcn_s_setprio(1);
#pragma unroll
            for (int n = 0; n < 4; ++n)
                s[n] = __builtin_amdgcn_mfma_f32_16x16x32_bf16(aq, frag32(L + kOff, n * 16 + l15, l4 * 8), zero4, 0, 0, 0);
            __builtin_amdgcn_s_setprio(0);
            const bool needMask = (kt >= 2 * Qt);
#pragma unroll
            for (int n = 0; n < 4; ++n)
#pragma unroll
                for (int r = 0; r < 4; ++r) {
                    const float d = s[n][r];
                    float sc = 1.f + 0.25f * d + d * d * (1.f / 32.f);
                    if (needMask) {
                        const int tg = kt * 64 + n * 16 + l15;
                        if (tg > sgBase + r) sc = 0.f;
                    }
                    const int prow = l4 * 4 + r;
                    const int pcol = n * 16 + l15;
                    const int ch = pcol >> 3;
                    *(bf16g*)(Pw + prow * 128 + ((ch ^ (prow & 7)) << 4) + (pcol & 7) * 2) =
                        __float2bfloat16(sc);
                }
            __builtin_amdgcn_s_setprio(1);
#pragma unroll
            for (int kk = 0; kk < 2; ++kk) {
                bf16x8 pa = frag64(Pw, l15, kk * 32 + l4 * 8);
#pragma unroll
                for (int n = 0; n < 4; ++n)
                    acc[n] = __builtin_amdgcn_mfma_f32_16x16x32_bf16(
                        pa, frag64(L + vOff, n * 16 + l15, kk * 32 + l4 * 8), acc[n], 0, 0, 0);
                accl = __builtin_amdgcn_mfma_f32_16x16x32_bf16(pa, vones, accl, 0, 0, 0);
            }
            __builtin_amdgcn_s_setprio(0);
            if (kt < ktEnd && tid < 256)
                *(uint4*)(L + (16384 + (cur ^ 1) * 4096) + row * 64 + gp * 16) = knext;
            __syncthreads();
            cur ^= 1;
        }
#pragma unroll
        for (int n = 0; n < 4; ++n)
#pragma unroll
            for (int r = 0; r < 4; ++r) {
                const int sg = sgBase + r;
                att[(size_t)sg * 2048 + h * 64 + n * 16 + l15] =
                    __float2bfloat16(acc[n][r] / (accl[r] + 1e-9f));
            }
    }
}

// ------------------- host -------------------
extern "C" void kernel_launch(void* const* d_in, const int* in_sizes, int n_in,
                              void* d_out, int out_size, void* d_ws, size_t ws_size,
                              hipStream_t stream) {
    const float* h      = (const float*)d_in[0];
    const int*   amask  = (const int*)d_in[1];
    const float* lin_Wq = (const float*)d_in[2];
    const float* lin_Wk = (const float*)d_in[3];
    const float* lin_Wv = (const float*)d_in[4];
    const float* lin_Wo = (const float*)d_in[5];
    const float* win_Wq = (const float*)d_in[6];
    const float* win_Wk = (const float*)d_in[7];
    const float* win_Wv = (const float*)d_in[8];
    const float* win_Wo = (const float*)d_in[9];
    float* out = (float*)d_out;

    char* p = (char*)d_ws;
    bf16g* h_b   = (bf16g*)p; p += (size_t)SEQ * DIM * 2;
    bf16g* BT    = (bf16g*)p; p += (size_t)QS * DIM * 2;     // fused [4608][1024]
    bf16g* WoT   = (bf16g*)p; p += (size_t)DIM * 2048 * 2;
    bf16g* qkv   = (bf16g*)p; p += (size_t)SEQ * QS * 2;     // fused [2048][4608]
    bf16g* vlinT = (bf16g*)p; p += (size_t)DIM * SEQ * 2;
    bf16g* vwT   = (bf16g*)p; p += (size_t)DIM * SEQ * 2;
    bf16g* att   = (bf16g*)p; p += (size_t)SEQ * 2048 * 2;
    float* bias  = (float*)p; p += (size_t)SEQ * 4;

    const dim3 blk(256);
    convert_h<<<dim3(SEQ * DIM / 8 / 256), blk, 0, stream>>>(h, h_b);

    transpose_f32_bf16<<<dim3(8, 32), blk, 0, stream>>>(lin_Wq, BT, DIM, 256, DIM);
    transpose_f32_bf16<<<dim3(8, 32), blk, 0, stream>>>(lin_Wk, BT + (size_t)256 * DIM, DIM, 256, DIM);
    TP6 jobs;
    jobs.src[0] = lin_Wv; jobs.dst[0] = BT + (size_t)512 * DIM;  jobs.os[0] = DIM;
    jobs.src[1] = win_Wq; jobs.dst[1] = BT + (size_t)1536 * DIM; jobs.os[1] = DIM;
    jobs.src[2] = win_Wk; jobs.dst[2] = BT + (size_t)2560 * DIM; jobs.os[2] = DIM;
    jobs.src[3] = win_Wv; jobs.dst[3] = BT + (size_t)3584 * DIM; jobs.os[3] = DIM;
    jobs.src[4] = lin_Wo; jobs.dst[4] = WoT;                     jobs.os[4] = 2048;
    jobs.src[5] = win_Wo; jobs.dst[5] = WoT + 1024;              jobs.os[5] = 2048;
    transpose6<<<dim3(32, 32, 6), blk, 0, stream>>>(jobs);
    make_bias<<<dim3(SEQ / 256), blk, 0, stream>>>(amask, bias);

    // single fused QKV projection GEMM: [2048][1024] @ [4608][1024]^T
    gemm_bf16<0><<<dim3(QS / 128, SEQ / 128), blk, 0, stream>>>(h_b, BT, nullptr, qkv, SEQ, QS, DIM);

    transposeV<<<dim3(32, 64, 2), blk, 0, stream>>>(qkv, vlinT, vwT);

    attn_fused<<<dim3(2 * SEQ / 128 * NH), dim3(512), 0, stream>>>(qkv, vlinT, vwT, bias, att);

    gemm_bf16<1><<<dim3(DIM / 128, SEQ / 128), blk, 0, stream>>>(att, WoT, out, nullptr, SEQ, DIM, 2048);
}